// Round 10
// baseline (585.232 us; speedup 1.0000x reference)
//
#include <hip/hip_runtime.h>
#include <hip/hip_bf16.h>
#include <hip/hip_fp16.h>

// N=4096 nodes, E=4096 hyperedges, F=256, H=256. All float tensors f32;
// batch_mask int32. out = 8192 f32: [pos_score | neg_score].

typedef short bf16x8 __attribute__((ext_vector_type(8)));
typedef float f32x4 __attribute__((ext_vector_type(4)));

static __device__ __forceinline__ unsigned short f2bf(float f) {
    __hip_bfloat16 b = __float2bfloat16(f);
    return __builtin_bit_cast(unsigned short, b);
}
static __device__ __forceinline__ float f16u_to_f(unsigned u) {
    __half h = __builtin_bit_cast(__half, (unsigned short)(u & 0xffffu));
    return __half2float(h);
}
// async global->LDS DMA, 16B per lane; LDS dest = wave-uniform base + lane*16
static __device__ __forceinline__ void gload_lds16(const void* g, void* l) {
    __builtin_amdgcn_global_load_lds(
        (const __attribute__((address_space(1))) unsigned*)g,
        (__attribute__((address_space(3))) unsigned*)l, 16, 0, 0);
}

// ---------------------------------------------------------------- transpose W (f32 -> bf16)
__global__ void k_transpose(const float* __restrict__ Ws, const float* __restrict__ Wh,
                            unsigned short* __restrict__ Wts, unsigned short* __restrict__ Wth) {
    int k = blockIdx.x;
    int n = threadIdx.x;
    const float* W     = blockIdx.y ? Wh : Ws;
    unsigned short* Wt = blockIdx.y ? Wth : Wts;
    Wt[n * 256 + k] = f2bf(W[k * 256 + n]);
}

// ---------------------------------------------------------------- pack mask -> bitwords
// INVERTED, MSB-first: bit (31-j) of packed[e][w] = !mask[e][w*32+j].
// Consumer: nm = (int)we >> 31 (~0 = NON-member = exclude), we += we.
__global__ void k_pack_mask(const int* __restrict__ mask, unsigned* __restrict__ packed) {
    int w = blockIdx.x * 256 + threadIdx.x;
    const int* p = mask + (size_t)w * 32;
    unsigned word = 0;
#pragma unroll
    for (int j = 0; j < 32; j += 4) {
        int4 m = *(const int4*)(p + j);
        word |= (m.x == 0 ? (1u << (31 - j)) : 0u)
              | (m.y == 0 ? (1u << (30 - j)) : 0u)
              | (m.z == 0 ? (1u << (29 - j)) : 0u)
              | (m.w == 0 ? (1u << (28 - j)) : 0u);
    }
    packed[w] = word;
}

// ---------------------------------------------------------------- GEMM + relu -> f16 h
__launch_bounds__(256)
__global__ void k_gemm_relu(const float* __restrict__ pXf, const float* __restrict__ pXm,
                            const float* __restrict__ nXf, const float* __restrict__ nXm,
                            const unsigned short* __restrict__ Wts, const unsigned short* __restrict__ Wth,
                            const float* __restrict__ bs,  const float* __restrict__ bh,
                            unsigned short* __restrict__ hAll /* f16 [2][4096][256] */) {
    const int t  = threadIdx.x;
    const int wv = t >> 6;
    const int l  = t & 63;
    const int lm = l & 15;
    const int q  = l >> 4;
    const int bz = blockIdx.z;
    const float* Xf = bz ? nXf : pXf;
    const float* Xm = bz ? nXm : pXm;
    unsigned short* hb = hAll + (size_t)bz * 4096 * 256;

    const int m0 = blockIdx.x * 64 + wv * 16;
    const int n0 = blockIdx.y * 64;

    f32x4 acc[4] = {};
#pragma unroll
    for (int ks = 0; ks < 512; ks += 32) {
        const float* X           = (ks < 256) ? Xf : Xm;
        const unsigned short* Wt = (ks < 256) ? Wts : Wth;
        const int kk = (ks & 255) + q * 8;
        float4 a0 = *(const float4*)(X + (m0 + lm) * 256 + kk);
        float4 a1 = *(const float4*)(X + (m0 + lm) * 256 + kk + 4);
        bf16x8 a;
        a[0] = (short)f2bf(a0.x); a[1] = (short)f2bf(a0.y);
        a[2] = (short)f2bf(a0.z); a[3] = (short)f2bf(a0.w);
        a[4] = (short)f2bf(a1.x); a[5] = (short)f2bf(a1.y);
        a[6] = (short)f2bf(a1.z); a[7] = (short)f2bf(a1.w);
#pragma unroll
        for (int nt = 0; nt < 4; nt++) {
            bf16x8 b = *(const bf16x8*)(Wt + (n0 + nt * 16 + lm) * 256 + kk);
            acc[nt] = __builtin_amdgcn_mfma_f32_16x16x32_bf16(a, b, acc[nt], 0, 0, 0);
        }
    }
#pragma unroll
    for (int nt = 0; nt < 4; nt++) {
        const int c = n0 + nt * 16 + lm;
        const float bsum = bs[c] + bh[c];
#pragma unroll
        for (int i = 0; i < 4; i++) {
            const int r = m0 + q * 4 + i;
            float v = acc[nt][i] + bsum;
            v = v > 0.f ? v : 0.f;   // relu => h >= +0.0 (u16-monotonic f16 bits)
            hb[r * 256 + c] = __builtin_bit_cast(unsigned short, __float2half(v));
        }
    }
}

// one (edge,node) update: 2 SALU + 6 VALU, fully pinned.
//   nm = (int)we >> 31 (~0 = non-member); we <<= 1
//   t = v|nm: nonmember = 0xFFFF/half -> loses v_pk_max_i16 (members >= 0)
//   AND loses v_pk_min_u16 (members <= 0x7C00).
#define POOL_STEP(WE, MX0, MX1, MN0, MN1, VX, VY)                          \
    {                                                                      \
        unsigned nm_, t0_, t1_;                                            \
        asm("s_ashr_i32 %[nm], %[we], 31\n\t"                              \
            "s_add_u32 %[we], %[we], %[we]\n\t"                            \
            "v_or_b32 %[t0], %[nm], %[vx]\n\t"                             \
            "v_or_b32 %[t1], %[nm], %[vy]\n\t"                             \
            "v_pk_max_i16 %[mx0], %[mx0], %[t0]\n\t"                       \
            "v_pk_max_i16 %[mx1], %[mx1], %[t1]\n\t"                       \
            "v_pk_min_u16 %[mn0], %[mn0], %[t0]\n\t"                       \
            "v_pk_min_u16 %[mn1], %[mn1], %[t1]"                           \
            : [nm] "=&s"(nm_), [we] "+s"(WE),                              \
              [t0] "=&v"(t0_), [t1] "=&v"(t1_),                            \
              [mx0] "+v"(MX0), [mx1] "+v"(MX1),                            \
              [mn0] "+v"(MN0), [mn1] "+v"(MN1)                             \
            : [vx] "v"(VX), [vy] "v"(VY)                                   \
            : "scc");                                                      \
    }

// ---------------------------------------------------------------- pool + score
// Block: 16 edges x 256 cols x one branch. 4 waves; wave wv owns edges
// e0+4wv..+3 and scans ALL 4096 nodes (per-wave-complete, no merge).
// Lane l holds cols 4l..4l+3 as two packed u32. Per (edge,node): POOL_STEP
// (asm-pinned 2 SALU + 6 VALU; round-9's C version bloated to ~13/edge).
// Staging: 32-node chunks (16 KB) double-buffered via global_load_lds DMA.
// grid (256, 2), block 256. LDS 40 KB.
__launch_bounds__(256)
__global__ void k_pool6(const unsigned short* __restrict__ hAll,
                        const unsigned* __restrict__ packed,
                        const float* __restrict__ Wscore,
                        const float* __restrict__ bscore,
                        float* __restrict__ out) {
    __shared__ __align__(16) unsigned bits[16 * 128];      // 8 KB
    __shared__ __align__(16) unsigned hch[2][32 * 128];    // 2 x 16 KB

    const int t  = threadIdx.x;
    const int wv = t >> 6;
    const int l  = t & 63;
    const int e0 = blockIdx.x * 16;
    const int br = blockIdx.y;
    const unsigned short* h = hAll + (size_t)br * 4096 * 256;
    const uint4* hsrc = (const uint4*)h;   // 1024 uint4 per 32-node chunk

    // stage mask bits for 16 edges: 2048 u32 = 512 uint4
    ((uint4*)bits)[t]       = ((const uint4*)(packed + e0 * 128))[t];
    ((uint4*)bits)[t + 256] = ((const uint4*)(packed + e0 * 128))[t + 256];

    unsigned mx0[4], mx1[4], mn0[4], mn1[4];
#pragma unroll
    for (int e = 0; e < 4; e++) {
        mx0[e] = 0x80008000u; mx1[e] = 0x80008000u;
        mn0[e] = 0xFFFFFFFFu; mn1[e] = 0xFFFFFFFFu;
    }

    // issue DMA for chunk 0 into buffer 0
#pragma unroll
    for (int i = 0; i < 4; i++)
        gload_lds16(&hsrc[wv * 256 + i * 64 + l], &hch[0][(wv * 256 + i * 64) * 4]);

    const int rowb = wv * 4 * 128;   // bits row base for this wave's 4 edges

    for (int ch = 0; ch < 128; ch++) {
        const unsigned* buf = hch[ch & 1];
        __syncthreads();   // drains chunk ch's DMA; orders buffer reuse

        if (ch < 127) {
            unsigned* nb = hch[(ch + 1) & 1];
#pragma unroll
            for (int i = 0; i < 4; i++)
                gload_lds16(&hsrc[(ch + 1) * 1024 + wv * 256 + i * 64 + l],
                            &nb[(wv * 256 + i * 64) * 4]);
        }

        // SGPR shift registers, one readfirstlane per edge per 32-node chunk
        unsigned we0 = (unsigned)__builtin_amdgcn_readfirstlane((int)bits[rowb + 0 * 128 + ch]);
        unsigned we1 = (unsigned)__builtin_amdgcn_readfirstlane((int)bits[rowb + 1 * 128 + ch]);
        unsigned we2 = (unsigned)__builtin_amdgcn_readfirstlane((int)bits[rowb + 2 * 128 + ch]);
        unsigned we3 = (unsigned)__builtin_amdgcn_readfirstlane((int)bits[rowb + 3 * 128 + ch]);

#pragma unroll
        for (int j = 0; j < 32; j++) {
            uint2 v = *(const uint2*)&buf[j * 128 + 2 * l];
            POOL_STEP(we0, mx0[0], mx1[0], mn0[0], mn1[0], v.x, v.y);
            POOL_STEP(we1, mx0[1], mx1[1], mn0[1], mn1[1], v.x, v.y);
            POOL_STEP(we2, mx0[2], mx1[2], mn0[2], mn1[2], v.x, v.y);
            POOL_STEP(we3, mx0[3], mx1[3], mn0[3], mn1[3], v.x, v.y);
        }
    }

    // epilogue: per-wave-complete; dot + sigmoid
    float4 wsv = *(const float4*)(Wscore + 4 * l);
    const float bsc = *bscore;
#pragma unroll
    for (int e = 0; e < 4; e++) {
        float s = (f16u_to_f(mx0[e])       - f16u_to_f(mn0[e]))       * wsv.x
                + (f16u_to_f(mx0[e] >> 16) - f16u_to_f(mn0[e] >> 16)) * wsv.y
                + (f16u_to_f(mx1[e])       - f16u_to_f(mn1[e]))       * wsv.z
                + (f16u_to_f(mx1[e] >> 16) - f16u_to_f(mn1[e] >> 16)) * wsv.w;
#pragma unroll
        for (int off = 32; off; off >>= 1) s += __shfl_xor(s, off);
        if (l == 0)
            out[br * 4096 + e0 + wv * 4 + e] = 1.f / (1.f + __expf(-(s + bsc)));
    }
}

// ---------------------------------------------------------------- launch
extern "C" void kernel_launch(void* const* d_in, const int* in_sizes, int n_in,
                              void* d_out, int out_size, void* d_ws, size_t ws_size,
                              hipStream_t stream) {
    const float* pf  = (const float*)d_in[0];
    const float* pm  = (const float*)d_in[1];
    const float* nf  = (const float*)d_in[2];
    const float* nm  = (const float*)d_in[3];
    const int*   msk = (const int*)d_in[4];
    const float* Wsf = (const float*)d_in[5];
    const float* bsf = (const float*)d_in[6];
    const float* Whp = (const float*)d_in[7];
    const float* bhp = (const float*)d_in[8];
    const float* Wsc = (const float*)d_in[9];
    const float* bsc = (const float*)d_in[10];
    float* out = (float*)d_out;

    char* ws = (char*)d_ws;
    unsigned short* hbuf = (unsigned short*)ws;                                   // 4 MB
    unsigned short* Wts  = (unsigned short*)(ws + 4u * 1024 * 1024);              // 128 KB
    unsigned short* Wth  = Wts + 256 * 256;                                       // 128 KB
    unsigned*       pck  = (unsigned*)(ws + 4u * 1024 * 1024 + 512u * 1024);      // 2 MB

    k_transpose<<<dim3(256, 2), 256, 0, stream>>>(Wsf, Whp, Wts, Wth);
    k_pack_mask<<<2048, 256, 0, stream>>>(msk, pck);
    k_gemm_relu<<<dim3(64, 4, 2), 256, 0, stream>>>(pf, pm, nf, nm, Wts, Wth, bsf, bhp, hbuf);
    k_pool6<<<dim3(256, 2), 256, 0, stream>>>(hbuf, pck, Wsc, bsc, out);
}

// Round 11
// 510.535 us; speedup vs baseline: 1.1463x; 1.1463x over previous
//
#include <hip/hip_runtime.h>
#include <hip/hip_bf16.h>
#include <hip/hip_fp16.h>

// N=4096 nodes, E=4096 hyperedges, F=256, H=256. All float tensors f32;
// batch_mask int32. out = 8192 f32: [pos_score | neg_score].

typedef short bf16x8 __attribute__((ext_vector_type(8)));
typedef float f32x4 __attribute__((ext_vector_type(4)));
typedef short s16x2 __attribute__((ext_vector_type(2)));
typedef unsigned short u16x2 __attribute__((ext_vector_type(2)));

static __device__ __forceinline__ unsigned short f2bf(float f) {
    __hip_bfloat16 b = __float2bfloat16(f);
    return __builtin_bit_cast(unsigned short, b);
}
static __device__ __forceinline__ float f16u_to_f(unsigned u) {
    __half h = __builtin_bit_cast(__half, (unsigned short)(u & 0xffffu));
    return __half2float(h);
}
static __device__ __forceinline__ unsigned pkmax_i16(unsigned a, unsigned b) {
    s16x2 r = __builtin_elementwise_max(__builtin_bit_cast(s16x2, a), __builtin_bit_cast(s16x2, b));
    return __builtin_bit_cast(unsigned, r);
}
static __device__ __forceinline__ unsigned pkmin_u16(unsigned a, unsigned b) {
    u16x2 r = __builtin_elementwise_min(__builtin_bit_cast(u16x2, a), __builtin_bit_cast(u16x2, b));
    return __builtin_bit_cast(unsigned, r);
}

// ---------------------------------------------------------------- transpose W (f32 -> bf16)
__global__ void k_transpose(const float* __restrict__ Ws, const float* __restrict__ Wh,
                            unsigned short* __restrict__ Wts, unsigned short* __restrict__ Wth) {
    int k = blockIdx.x;
    int n = threadIdx.x;
    const float* W     = blockIdx.y ? Wh : Ws;
    unsigned short* Wt = blockIdx.y ? Wth : Wts;
    Wt[n * 256 + k] = f2bf(W[k * 256 + n]);
}

// ---------------------------------------------------------------- pack mask -> bitwords
// INVERTED, MSB-first: bit (31-j) of packed[e][w] = !mask[e][w*32+j].
// Consumer: nm = (int)we >> 31 (~0 = NON-member = exclude), we += we.
__global__ void k_pack_mask(const int* __restrict__ mask, unsigned* __restrict__ packed) {
    int w = blockIdx.x * 256 + threadIdx.x;
    const int* p = mask + (size_t)w * 32;
    unsigned word = 0;
#pragma unroll
    for (int j = 0; j < 32; j += 4) {
        int4 m = *(const int4*)(p + j);
        word |= (m.x == 0 ? (1u << (31 - j)) : 0u)
              | (m.y == 0 ? (1u << (30 - j)) : 0u)
              | (m.z == 0 ? (1u << (29 - j)) : 0u)
              | (m.w == 0 ? (1u << (28 - j)) : 0u);
    }
    packed[w] = word;
}

// ---------------------------------------------------------------- GEMM + relu -> f16 h
__launch_bounds__(256)
__global__ void k_gemm_relu(const float* __restrict__ pXf, const float* __restrict__ pXm,
                            const float* __restrict__ nXf, const float* __restrict__ nXm,
                            const unsigned short* __restrict__ Wts, const unsigned short* __restrict__ Wth,
                            const float* __restrict__ bs,  const float* __restrict__ bh,
                            unsigned short* __restrict__ hAll /* f16 [2][4096][256] */) {
    const int t  = threadIdx.x;
    const int wv = t >> 6;
    const int l  = t & 63;
    const int lm = l & 15;
    const int q  = l >> 4;
    const int bz = blockIdx.z;
    const float* Xf = bz ? nXf : pXf;
    const float* Xm = bz ? nXm : pXm;
    unsigned short* hb = hAll + (size_t)bz * 4096 * 256;

    const int m0 = blockIdx.x * 64 + wv * 16;
    const int n0 = blockIdx.y * 64;

    f32x4 acc[4] = {};
#pragma unroll
    for (int ks = 0; ks < 512; ks += 32) {
        const float* X           = (ks < 256) ? Xf : Xm;
        const unsigned short* Wt = (ks < 256) ? Wts : Wth;
        const int kk = (ks & 255) + q * 8;
        float4 a0 = *(const float4*)(X + (m0 + lm) * 256 + kk);
        float4 a1 = *(const float4*)(X + (m0 + lm) * 256 + kk + 4);
        bf16x8 a;
        a[0] = (short)f2bf(a0.x); a[1] = (short)f2bf(a0.y);
        a[2] = (short)f2bf(a0.z); a[3] = (short)f2bf(a0.w);
        a[4] = (short)f2bf(a1.x); a[5] = (short)f2bf(a1.y);
        a[6] = (short)f2bf(a1.z); a[7] = (short)f2bf(a1.w);
#pragma unroll
        for (int nt = 0; nt < 4; nt++) {
            bf16x8 b = *(const bf16x8*)(Wt + (n0 + nt * 16 + lm) * 256 + kk);
            acc[nt] = __builtin_amdgcn_mfma_f32_16x16x32_bf16(a, b, acc[nt], 0, 0, 0);
        }
    }
#pragma unroll
    for (int nt = 0; nt < 4; nt++) {
        const int c = n0 + nt * 16 + lm;
        const float bsum = bs[c] + bh[c];
#pragma unroll
        for (int i = 0; i < 4; i++) {
            const int r = m0 + q * 4 + i;
            float v = acc[nt][i] + bsum;
            v = v > 0.f ? v : 0.f;   // relu => h >= +0.0 (u16-monotonic f16 bits)
            hb[r * 256 + c] = __builtin_bit_cast(unsigned short, __float2half(v));
        }
    }
}

// one (edge,node) update: 2 SALU + 6 VALU, fully pinned (round-10 proven).
//   nm = (int)we >> 31 (~0 = non-member); we <<= 1
//   t = v|nm: nonmember = 0xFFFF/half -> loses v_pk_max_i16 (members >= 0)
//   AND loses v_pk_min_u16 (members <= 0x7C00).
#define POOL_STEP(WE, MX0, MX1, MN0, MN1, VX, VY)                          \
    {                                                                      \
        unsigned nm_, t0_, t1_;                                            \
        asm("s_ashr_i32 %[nm], %[we], 31\n\t"                              \
            "s_add_u32 %[we], %[we], %[we]\n\t"                            \
            "v_or_b32 %[t0], %[nm], %[vx]\n\t"                             \
            "v_or_b32 %[t1], %[nm], %[vy]\n\t"                             \
            "v_pk_max_i16 %[mx0], %[mx0], %[t0]\n\t"                       \
            "v_pk_max_i16 %[mx1], %[mx1], %[t1]\n\t"                       \
            "v_pk_min_u16 %[mn0], %[mn0], %[t0]\n\t"                       \
            "v_pk_min_u16 %[mn1], %[mn1], %[t1]"                           \
            : [nm] "=&s"(nm_), [we] "+s"(WE),                              \
              [t0] "=&v"(t0_), [t1] "=&v"(t1_),                            \
              [mx0] "+v"(MX0), [mx1] "+v"(MX1),                            \
              [mn0] "+v"(MN0), [mn1] "+v"(MN1)                             \
            : [vx] "v"(VX), [vy] "v"(VY)                                   \
            : "scc");                                                      \
    }

// ---------------------------------------------------------------- pool + score
// Node-split for occupancy: block = 4 edges x one branch; 4 waves, wave wv
// covers node quarter [wv*1024, +1024) for ALL 4 edges. grid (1024, 2) =
// 2048 blocks = 8 blocks/CU = 8 waves/SIMD (vs round-10's 2: grid-limited).
// h read DIRECTLY from L2 (global_load_dwordx2, consumed in batches of 4 --
// nothing to spill); no DMA, no main-loop barriers. Lane l holds cols
// 4l..4l+3. Select via SGPR shift register + POOL_STEP asm.
// Merge: per-wave partials -> LDS (16 KB), one barrier, wave wv reduces
// edge wv (4x ds_read_b128 + pk ops), dot + shuffle + sigmoid.
// LDS 18 KB. __launch_bounds__(256,8) caps VGPR <= 64.
__launch_bounds__(256, 8)
__global__ void k_pool7(const unsigned short* __restrict__ hAll,
                        const unsigned* __restrict__ packed,
                        const float* __restrict__ Wscore,
                        const float* __restrict__ bscore,
                        float* __restrict__ out) {
    __shared__ __align__(16) unsigned bits[4 * 128];           // 2 KB
    __shared__ __align__(16) unsigned part[4][4][64][4];       // [wv][e][lane][4] = 16 KB

    const int t  = threadIdx.x;
    const int wv = t >> 6;
    const int l  = t & 63;
    const int e0 = blockIdx.x * 4;
    const int br = blockIdx.y;
    const unsigned short* h = hAll + (size_t)br * 4096 * 256;

    // stage mask bits for 4 edges: 512 u32 = 128 uint4
    if (t < 128) ((uint4*)bits)[t] = ((const uint4*)(packed + e0 * 128))[t];
    __syncthreads();

    unsigned mx0[4], mx1[4], mn0[4], mn1[4];
#pragma unroll
    for (int e = 0; e < 4; e++) {
        mx0[e] = 0x80008000u; mx1[e] = 0x80008000u;
        mn0[e] = 0xFFFFFFFFu; mn1[e] = 0xFFFFFFFFu;
    }

    // wave wv scans nodes [wv*1024, +1024) in 32-node chunks
    for (int ch = 0; ch < 32; ch++) {
        unsigned we0 = (unsigned)__builtin_amdgcn_readfirstlane((int)bits[0 * 128 + wv * 32 + ch]);
        unsigned we1 = (unsigned)__builtin_amdgcn_readfirstlane((int)bits[1 * 128 + wv * 32 + ch]);
        unsigned we2 = (unsigned)__builtin_amdgcn_readfirstlane((int)bits[2 * 128 + wv * 32 + ch]);
        unsigned we3 = (unsigned)__builtin_amdgcn_readfirstlane((int)bits[3 * 128 + wv * 32 + ch]);

        const unsigned short* hp = h + (size_t)(wv * 1024 + ch * 32) * 256 + 4 * l;
#pragma unroll
        for (int jj = 0; jj < 8; jj++) {
            // batch 4 node loads (8 VGPRs live; compiler pipelines via vmcnt)
            uint2 v0 = *(const uint2*)(hp + (jj * 4 + 0) * 256);
            uint2 v1 = *(const uint2*)(hp + (jj * 4 + 1) * 256);
            uint2 v2 = *(const uint2*)(hp + (jj * 4 + 2) * 256);
            uint2 v3 = *(const uint2*)(hp + (jj * 4 + 3) * 256);

            POOL_STEP(we0, mx0[0], mx1[0], mn0[0], mn1[0], v0.x, v0.y);
            POOL_STEP(we1, mx0[1], mx1[1], mn0[1], mn1[1], v0.x, v0.y);
            POOL_STEP(we2, mx0[2], mx1[2], mn0[2], mn1[2], v0.x, v0.y);
            POOL_STEP(we3, mx0[3], mx1[3], mn0[3], mn1[3], v0.x, v0.y);

            POOL_STEP(we0, mx0[0], mx1[0], mn0[0], mn1[0], v1.x, v1.y);
            POOL_STEP(we1, mx0[1], mx1[1], mn0[1], mn1[1], v1.x, v1.y);
            POOL_STEP(we2, mx0[2], mx1[2], mn0[2], mn1[2], v1.x, v1.y);
            POOL_STEP(we3, mx0[3], mx1[3], mn0[3], mn1[3], v1.x, v1.y);

            POOL_STEP(we0, mx0[0], mx1[0], mn0[0], mn1[0], v2.x, v2.y);
            POOL_STEP(we1, mx0[1], mx1[1], mn0[1], mn1[1], v2.x, v2.y);
            POOL_STEP(we2, mx0[2], mx1[2], mn0[2], mn1[2], v2.x, v2.y);
            POOL_STEP(we3, mx0[3], mx1[3], mn0[3], mn1[3], v2.x, v2.y);

            POOL_STEP(we0, mx0[0], mx1[0], mn0[0], mn1[0], v3.x, v3.y);
            POOL_STEP(we1, mx0[1], mx1[1], mn0[1], mn1[1], v3.x, v3.y);
            POOL_STEP(we2, mx0[2], mx1[2], mn0[2], mn1[2], v3.x, v3.y);
            POOL_STEP(we3, mx0[3], mx1[3], mn0[3], mn1[3], v3.x, v3.y);
        }
    }

    // write per-wave partials to LDS
#pragma unroll
    for (int e = 0; e < 4; e++) {
        uint4 p; p.x = mx0[e]; p.y = mx1[e]; p.z = mn0[e]; p.w = mn1[e];
        *(uint4*)&part[wv][e][l][0] = p;
    }
    __syncthreads();

    // wave wv reduces edge wv across the 4 node-quarter partials
    unsigned rmx0 = 0x80008000u, rmx1 = 0x80008000u;
    unsigned rmn0 = 0xFFFFFFFFu, rmn1 = 0xFFFFFFFFu;
#pragma unroll
    for (int w2 = 0; w2 < 4; w2++) {
        uint4 p = *(const uint4*)&part[w2][wv][l][0];
        rmx0 = pkmax_i16(rmx0, p.x);  rmx1 = pkmax_i16(rmx1, p.y);
        rmn0 = pkmin_u16(rmn0, p.z);  rmn1 = pkmin_u16(rmn1, p.w);
    }

    // dot + sigmoid
    float4 wsv = *(const float4*)(Wscore + 4 * l);
    const float bsc = *bscore;
    float s = (f16u_to_f(rmx0)       - f16u_to_f(rmn0))       * wsv.x
            + (f16u_to_f(rmx0 >> 16) - f16u_to_f(rmn0 >> 16)) * wsv.y
            + (f16u_to_f(rmx1)       - f16u_to_f(rmn1))       * wsv.z
            + (f16u_to_f(rmx1 >> 16) - f16u_to_f(rmn1 >> 16)) * wsv.w;
#pragma unroll
    for (int off = 32; off; off >>= 1) s += __shfl_xor(s, off);
    if (l == 0)
        out[br * 4096 + e0 + wv] = 1.f / (1.f + __expf(-(s + bsc)));
}

// ---------------------------------------------------------------- launch
extern "C" void kernel_launch(void* const* d_in, const int* in_sizes, int n_in,
                              void* d_out, int out_size, void* d_ws, size_t ws_size,
                              hipStream_t stream) {
    const float* pf  = (const float*)d_in[0];
    const float* pm  = (const float*)d_in[1];
    const float* nf  = (const float*)d_in[2];
    const float* nm  = (const float*)d_in[3];
    const int*   msk = (const int*)d_in[4];
    const float* Wsf = (const float*)d_in[5];
    const float* bsf = (const float*)d_in[6];
    const float* Whp = (const float*)d_in[7];
    const float* bhp = (const float*)d_in[8];
    const float* Wsc = (const float*)d_in[9];
    const float* bsc = (const float*)d_in[10];
    float* out = (float*)d_out;

    char* ws = (char*)d_ws;
    unsigned short* hbuf = (unsigned short*)ws;                                   // 4 MB
    unsigned short* Wts  = (unsigned short*)(ws + 4u * 1024 * 1024);              // 128 KB
    unsigned short* Wth  = Wts + 256 * 256;                                       // 128 KB
    unsigned*       pck  = (unsigned*)(ws + 4u * 1024 * 1024 + 512u * 1024);      // 2 MB

    k_transpose<<<dim3(256, 2), 256, 0, stream>>>(Wsf, Whp, Wts, Wth);
    k_pack_mask<<<2048, 256, 0, stream>>>(msk, pck);
    k_gemm_relu<<<dim3(64, 4, 2), 256, 0, stream>>>(pf, pm, nf, nm, Wts, Wth, bsf, bhp, hbuf);
    k_pool7<<<dim3(1024, 2), 256, 0, stream>>>(hbuf, pck, Wsc, bsc, out);
}

// Round 12
// 399.043 us; speedup vs baseline: 1.4666x; 1.2794x over previous
//
#include <hip/hip_runtime.h>
#include <hip/hip_bf16.h>
#include <hip/hip_fp16.h>

// N=4096 nodes, E=4096 hyperedges, F=256, H=256. All float tensors f32;
// batch_mask int32. out = 8192 f32: [pos_score | neg_score].

typedef short bf16x8 __attribute__((ext_vector_type(8)));
typedef float f32x4 __attribute__((ext_vector_type(4)));
typedef short s16x2 __attribute__((ext_vector_type(2)));
typedef unsigned short u16x2 __attribute__((ext_vector_type(2)));

static __device__ __forceinline__ unsigned short f2bf(float f) {
    __hip_bfloat16 b = __float2bfloat16(f);
    return __builtin_bit_cast(unsigned short, b);
}
static __device__ __forceinline__ float f16u_to_f(unsigned u) {
    __half h = __builtin_bit_cast(__half, (unsigned short)(u & 0xffffu));
    return __half2float(h);
}
static __device__ __forceinline__ unsigned pkmax_i16(unsigned a, unsigned b) {
    s16x2 r = __builtin_elementwise_max(__builtin_bit_cast(s16x2, a), __builtin_bit_cast(s16x2, b));
    return __builtin_bit_cast(unsigned, r);
}
static __device__ __forceinline__ unsigned pkmin_u16(unsigned a, unsigned b) {
    u16x2 r = __builtin_elementwise_min(__builtin_bit_cast(u16x2, a), __builtin_bit_cast(u16x2, b));
    return __builtin_bit_cast(unsigned, r);
}

// ---------------------------------------------------------------- transpose W (f32 -> bf16)
__global__ void k_transpose(const float* __restrict__ Ws, const float* __restrict__ Wh,
                            unsigned short* __restrict__ Wts, unsigned short* __restrict__ Wth) {
    int k = blockIdx.x;
    int n = threadIdx.x;
    const float* W     = blockIdx.y ? Wh : Ws;
    unsigned short* Wt = blockIdx.y ? Wth : Wts;
    Wt[n * 256 + k] = f2bf(W[k * 256 + n]);
}

// ---------------------------------------------------------------- pack mask -> bitwords
// NON-inverted, MSB-first: bit (31-j) of packed[e][w] = mask[e][w*32+j].
// Consumer: s_bitcmp1(we,31) = membership of current node; we += we advances.
__global__ void k_pack_mask(const int* __restrict__ mask, unsigned* __restrict__ packed) {
    int w = blockIdx.x * 256 + threadIdx.x;
    const int* p = mask + (size_t)w * 32;
    unsigned word = 0;
#pragma unroll
    for (int j = 0; j < 32; j += 4) {
        int4 m = *(const int4*)(p + j);
        word |= (m.x != 0 ? (1u << (31 - j)) : 0u)
              | (m.y != 0 ? (1u << (30 - j)) : 0u)
              | (m.z != 0 ? (1u << (29 - j)) : 0u)
              | (m.w != 0 ? (1u << (28 - j)) : 0u);
    }
    packed[w] = word;
}

// ---------------------------------------------------------------- GEMM + relu -> f16 h
__launch_bounds__(256)
__global__ void k_gemm_relu(const float* __restrict__ pXf, const float* __restrict__ pXm,
                            const float* __restrict__ nXf, const float* __restrict__ nXm,
                            const unsigned short* __restrict__ Wts, const unsigned short* __restrict__ Wth,
                            const float* __restrict__ bs,  const float* __restrict__ bh,
                            unsigned short* __restrict__ hAll /* f16 [2][4096][256] */) {
    const int t  = threadIdx.x;
    const int wv = t >> 6;
    const int l  = t & 63;
    const int lm = l & 15;
    const int q  = l >> 4;
    const int bz = blockIdx.z;
    const float* Xf = bz ? nXf : pXf;
    const float* Xm = bz ? nXm : pXm;
    unsigned short* hb = hAll + (size_t)bz * 4096 * 256;

    const int m0 = blockIdx.x * 64 + wv * 16;
    const int n0 = blockIdx.y * 64;

    f32x4 acc[4] = {};
#pragma unroll
    for (int ks = 0; ks < 512; ks += 32) {
        const float* X           = (ks < 256) ? Xf : Xm;
        const unsigned short* Wt = (ks < 256) ? Wts : Wth;
        const int kk = (ks & 255) + q * 8;
        float4 a0 = *(const float4*)(X + (m0 + lm) * 256 + kk);
        float4 a1 = *(const float4*)(X + (m0 + lm) * 256 + kk + 4);
        bf16x8 a;
        a[0] = (short)f2bf(a0.x); a[1] = (short)f2bf(a0.y);
        a[2] = (short)f2bf(a0.z); a[3] = (short)f2bf(a0.w);
        a[4] = (short)f2bf(a1.x); a[5] = (short)f2bf(a1.y);
        a[6] = (short)f2bf(a1.z); a[7] = (short)f2bf(a1.w);
#pragma unroll
        for (int nt = 0; nt < 4; nt++) {
            bf16x8 b = *(const bf16x8*)(Wt + (n0 + nt * 16 + lm) * 256 + kk);
            acc[nt] = __builtin_amdgcn_mfma_f32_16x16x32_bf16(a, b, acc[nt], 0, 0, 0);
        }
    }
#pragma unroll
    for (int nt = 0; nt < 4; nt++) {
        const int c = n0 + nt * 16 + lm;
        const float bsum = bs[c] + bh[c];
#pragma unroll
        for (int i = 0; i < 4; i++) {
            const int r = m0 + q * 4 + i;
            float v = acc[nt][i] + bsum;
            v = v > 0.f ? v : 0.f;   // relu => h >= +0.0 (u16-monotonic f16 bits)
            hb[r * 256 + c] = __builtin_bit_cast(unsigned short, __float2half(v));
        }
    }
}

// one (edge,node) update with member-skip (~50% density):
//   SCC = we[31] (membership, MSB-first non-inverted pack);
//   if member: 4 pk ops on v directly (no select needed);
//   we <<= 1 AFTER the branch (its SCC write is then harmless).
// member: 3 SALU-slot + 4 VALU; non-member: 3 SALU-slot + 0 VALU.
#define POOL_STEP(WE, MX0, MX1, MN0, MN1, VX, VY)                          \
    {                                                                      \
        asm("s_bitcmp1_b32 %[we], 31\n\t"                                  \
            "s_cbranch_scc0 Lskip%=\n\t"                                   \
            "v_pk_max_i16 %[mx0], %[mx0], %[vx]\n\t"                       \
            "v_pk_max_i16 %[mx1], %[mx1], %[vy]\n\t"                       \
            "v_pk_min_u16 %[mn0], %[mn0], %[vx]\n\t"                       \
            "v_pk_min_u16 %[mn1], %[mn1], %[vy]\n"                         \
            "Lskip%=:\n\t"                                                 \
            "s_add_u32 %[we], %[we], %[we]"                                \
            : [we] "+s"(WE),                                               \
              [mx0] "+v"(MX0), [mx1] "+v"(MX1),                            \
              [mn0] "+v"(MN0), [mn1] "+v"(MN1)                             \
            : [vx] "v"(VX), [vy] "v"(VY)                                   \
            : "scc");                                                      \
    }

// ---------------------------------------------------------------- pool + score
// Node-split (round-11 proven skeleton): block = 4 edges x one branch; 4
// waves, wave wv covers nodes [wv*1024, +1024) for ALL 4 edges. grid
// (1024, 2) = 8 blocks/CU. h read directly from L2 (global_load_dwordx2,
// batches of 4). Member-skip POOL_STEP cuts avg VALU/node-wave 26 -> ~10.
// Merge: per-wave partials -> LDS, one barrier, wave wv reduces edge wv,
// dot + shuffle + sigmoid. LDS 18 KB. __launch_bounds__(256,8).
__launch_bounds__(256, 8)
__global__ void k_pool8(const unsigned short* __restrict__ hAll,
                        const unsigned* __restrict__ packed,
                        const float* __restrict__ Wscore,
                        const float* __restrict__ bscore,
                        float* __restrict__ out) {
    __shared__ __align__(16) unsigned bits[4 * 128];           // 2 KB
    __shared__ __align__(16) unsigned part[4][4][64][4];       // [wv][e][lane][4] = 16 KB

    const int t  = threadIdx.x;
    const int wv = t >> 6;
    const int l  = t & 63;
    const int e0 = blockIdx.x * 4;
    const int br = blockIdx.y;
    const unsigned short* h = hAll + (size_t)br * 4096 * 256;

    // stage mask bits for 4 edges: 512 u32 = 128 uint4
    if (t < 128) ((uint4*)bits)[t] = ((const uint4*)(packed + e0 * 128))[t];
    __syncthreads();

    unsigned mx0[4], mx1[4], mn0[4], mn1[4];
#pragma unroll
    for (int e = 0; e < 4; e++) {
        mx0[e] = 0x80008000u; mx1[e] = 0x80008000u;   // -32768 i16: any member (>=0) wins
        mn0[e] = 0xFFFFFFFFu; mn1[e] = 0xFFFFFFFFu;   // 0xFFFF u16: any member (<=0x7C00) wins
    }

    // wave wv scans nodes [wv*1024, +1024) in 32-node chunks
#pragma unroll 1
    for (int ch = 0; ch < 32; ch++) {
        unsigned we0 = (unsigned)__builtin_amdgcn_readfirstlane((int)bits[0 * 128 + wv * 32 + ch]);
        unsigned we1 = (unsigned)__builtin_amdgcn_readfirstlane((int)bits[1 * 128 + wv * 32 + ch]);
        unsigned we2 = (unsigned)__builtin_amdgcn_readfirstlane((int)bits[2 * 128 + wv * 32 + ch]);
        unsigned we3 = (unsigned)__builtin_amdgcn_readfirstlane((int)bits[3 * 128 + wv * 32 + ch]);

        const unsigned short* hp = h + (size_t)(wv * 1024 + ch * 32) * 256 + 4 * l;
#pragma unroll
        for (int jj = 0; jj < 8; jj++) {
            // batch 4 node loads (8 VGPRs live; compiler pipelines via vmcnt)
            uint2 v0 = *(const uint2*)(hp + (jj * 4 + 0) * 256);
            uint2 v1 = *(const uint2*)(hp + (jj * 4 + 1) * 256);
            uint2 v2 = *(const uint2*)(hp + (jj * 4 + 2) * 256);
            uint2 v3 = *(const uint2*)(hp + (jj * 4 + 3) * 256);

            POOL_STEP(we0, mx0[0], mx1[0], mn0[0], mn1[0], v0.x, v0.y);
            POOL_STEP(we1, mx0[1], mx1[1], mn0[1], mn1[1], v0.x, v0.y);
            POOL_STEP(we2, mx0[2], mx1[2], mn0[2], mn1[2], v0.x, v0.y);
            POOL_STEP(we3, mx0[3], mx1[3], mn0[3], mn1[3], v0.x, v0.y);

            POOL_STEP(we0, mx0[0], mx1[0], mn0[0], mn1[0], v1.x, v1.y);
            POOL_STEP(we1, mx0[1], mx1[1], mn0[1], mn1[1], v1.x, v1.y);
            POOL_STEP(we2, mx0[2], mx1[2], mn0[2], mn1[2], v1.x, v1.y);
            POOL_STEP(we3, mx0[3], mx1[3], mn0[3], mn1[3], v1.x, v1.y);

            POOL_STEP(we0, mx0[0], mx1[0], mn0[0], mn1[0], v2.x, v2.y);
            POOL_STEP(we1, mx0[1], mx1[1], mn0[1], mn1[1], v2.x, v2.y);
            POOL_STEP(we2, mx0[2], mx1[2], mn0[2], mn1[2], v2.x, v2.y);
            POOL_STEP(we3, mx0[3], mx1[3], mn0[3], mn1[3], v2.x, v2.y);

            POOL_STEP(we0, mx0[0], mx1[0], mn0[0], mn1[0], v3.x, v3.y);
            POOL_STEP(we1, mx0[1], mx1[1], mn0[1], mn1[1], v3.x, v3.y);
            POOL_STEP(we2, mx0[2], mx1[2], mn0[2], mn1[2], v3.x, v3.y);
            POOL_STEP(we3, mx0[3], mx1[3], mn0[3], mn1[3], v3.x, v3.y);
        }
    }

    // write per-wave partials to LDS
#pragma unroll
    for (int e = 0; e < 4; e++) {
        uint4 p; p.x = mx0[e]; p.y = mx1[e]; p.z = mn0[e]; p.w = mn1[e];
        *(uint4*)&part[wv][e][l][0] = p;
    }
    __syncthreads();

    // wave wv reduces edge wv across the 4 node-quarter partials
    unsigned rmx0 = 0x80008000u, rmx1 = 0x80008000u;
    unsigned rmn0 = 0xFFFFFFFFu, rmn1 = 0xFFFFFFFFu;
#pragma unroll
    for (int w2 = 0; w2 < 4; w2++) {
        uint4 p = *(const uint4*)&part[w2][wv][l][0];
        rmx0 = pkmax_i16(rmx0, p.x);  rmx1 = pkmax_i16(rmx1, p.y);
        rmn0 = pkmin_u16(rmn0, p.z);  rmn1 = pkmin_u16(rmn1, p.w);
    }

    // dot + sigmoid
    float4 wsv = *(const float4*)(Wscore + 4 * l);
    const float bsc = *bscore;
    float s = (f16u_to_f(rmx0)       - f16u_to_f(rmn0))       * wsv.x
            + (f16u_to_f(rmx0 >> 16) - f16u_to_f(rmn0 >> 16)) * wsv.y
            + (f16u_to_f(rmx1)       - f16u_to_f(rmn1))       * wsv.z
            + (f16u_to_f(rmx1 >> 16) - f16u_to_f(rmn1 >> 16)) * wsv.w;
#pragma unroll
    for (int off = 32; off; off >>= 1) s += __shfl_xor(s, off);
    if (l == 0)
        out[br * 4096 + e0 + wv] = 1.f / (1.f + __expf(-(s + bsc)));
}

// ---------------------------------------------------------------- launch
extern "C" void kernel_launch(void* const* d_in, const int* in_sizes, int n_in,
                              void* d_out, int out_size, void* d_ws, size_t ws_size,
                              hipStream_t stream) {
    const float* pf  = (const float*)d_in[0];
    const float* pm  = (const float*)d_in[1];
    const float* nf  = (const float*)d_in[2];
    const float* nm  = (const float*)d_in[3];
    const int*   msk = (const int*)d_in[4];
    const float* Wsf = (const float*)d_in[5];
    const float* bsf = (const float*)d_in[6];
    const float* Whp = (const float*)d_in[7];
    const float* bhp = (const float*)d_in[8];
    const float* Wsc = (const float*)d_in[9];
    const float* bsc = (const float*)d_in[10];
    float* out = (float*)d_out;

    char* ws = (char*)d_ws;
    unsigned short* hbuf = (unsigned short*)ws;                                   // 4 MB
    unsigned short* Wts  = (unsigned short*)(ws + 4u * 1024 * 1024);              // 128 KB
    unsigned short* Wth  = Wts + 256 * 256;                                       // 128 KB
    unsigned*       pck  = (unsigned*)(ws + 4u * 1024 * 1024 + 512u * 1024);      // 2 MB

    k_transpose<<<dim3(256, 2), 256, 0, stream>>>(Wsf, Whp, Wts, Wth);
    k_pack_mask<<<2048, 256, 0, stream>>>(msk, pck);
    k_gemm_relu<<<dim3(64, 4, 2), 256, 0, stream>>>(pf, pm, nf, nm, Wts, Wth, bsf, bhp, hbuf);
    k_pool8<<<dim3(1024, 2), 256, 0, stream>>>(hbuf, pck, Wsc, bsc, out);
}

// Round 13
// 379.794 us; speedup vs baseline: 1.5409x; 1.0507x over previous
//
#include <hip/hip_runtime.h>
#include <hip/hip_bf16.h>
#include <hip/hip_fp16.h>

// N=4096 nodes, E=4096 hyperedges, F=256, H=256. All float tensors f32;
// batch_mask int32. out = 8192 f32: [pos_score | neg_score].

typedef short bf16x8 __attribute__((ext_vector_type(8)));
typedef float f32x4 __attribute__((ext_vector_type(4)));
typedef short s16x2 __attribute__((ext_vector_type(2)));
typedef unsigned short u16x2 __attribute__((ext_vector_type(2)));

static __device__ __forceinline__ unsigned short f2bf(float f) {
    __hip_bfloat16 b = __float2bfloat16(f);
    return __builtin_bit_cast(unsigned short, b);
}
static __device__ __forceinline__ float f16u_to_f(unsigned u) {
    __half h = __builtin_bit_cast(__half, (unsigned short)(u & 0xffffu));
    return __half2float(h);
}
static __device__ __forceinline__ unsigned pkmax_i16(unsigned a, unsigned b) {
    s16x2 r = __builtin_elementwise_max(__builtin_bit_cast(s16x2, a), __builtin_bit_cast(s16x2, b));
    return __builtin_bit_cast(unsigned, r);
}
static __device__ __forceinline__ unsigned pkmin_u16(unsigned a, unsigned b) {
    u16x2 r = __builtin_elementwise_min(__builtin_bit_cast(u16x2, a), __builtin_bit_cast(u16x2, b));
    return __builtin_bit_cast(unsigned, r);
}

// ---------------------------------------------------------------- transpose W (f32 -> bf16)
__global__ void k_transpose(const float* __restrict__ Ws, const float* __restrict__ Wh,
                            unsigned short* __restrict__ Wts, unsigned short* __restrict__ Wth) {
    int k = blockIdx.x;
    int n = threadIdx.x;
    const float* W     = blockIdx.y ? Wh : Ws;
    unsigned short* Wt = blockIdx.y ? Wth : Wts;
    Wt[n * 256 + k] = f2bf(W[k * 256 + n]);
}

// ---------------------------------------------------------------- pack mask -> bitwords
// NON-inverted, MSB-first: bit (31-j) of packed[e][w] = mask[e][w*32+j].
// Consumer: s_add_u32 we,we,we -> SCC = carry = old bit31 = membership.
__global__ void k_pack_mask(const int* __restrict__ mask, unsigned* __restrict__ packed) {
    int w = blockIdx.x * 256 + threadIdx.x;
    const int* p = mask + (size_t)w * 32;
    unsigned word = 0;
#pragma unroll
    for (int j = 0; j < 32; j += 4) {
        int4 m = *(const int4*)(p + j);
        word |= (m.x != 0 ? (1u << (31 - j)) : 0u)
              | (m.y != 0 ? (1u << (30 - j)) : 0u)
              | (m.z != 0 ? (1u << (29 - j)) : 0u)
              | (m.w != 0 ? (1u << (28 - j)) : 0u);
    }
    packed[w] = word;
}

// ---------------------------------------------------------------- GEMM + relu -> f16 h
__launch_bounds__(256)
__global__ void k_gemm_relu(const float* __restrict__ pXf, const float* __restrict__ pXm,
                            const float* __restrict__ nXf, const float* __restrict__ nXm,
                            const unsigned short* __restrict__ Wts, const unsigned short* __restrict__ Wth,
                            const float* __restrict__ bs,  const float* __restrict__ bh,
                            unsigned short* __restrict__ hAll /* f16 [2][4096][256] */) {
    const int t  = threadIdx.x;
    const int wv = t >> 6;
    const int l  = t & 63;
    const int lm = l & 15;
    const int q  = l >> 4;
    const int bz = blockIdx.z;
    const float* Xf = bz ? nXf : pXf;
    const float* Xm = bz ? nXm : pXm;
    unsigned short* hb = hAll + (size_t)bz * 4096 * 256;

    const int m0 = blockIdx.x * 64 + wv * 16;
    const int n0 = blockIdx.y * 64;

    f32x4 acc[4] = {};
#pragma unroll
    for (int ks = 0; ks < 512; ks += 32) {
        const float* X           = (ks < 256) ? Xf : Xm;
        const unsigned short* Wt = (ks < 256) ? Wts : Wth;
        const int kk = (ks & 255) + q * 8;
        float4 a0 = *(const float4*)(X + (m0 + lm) * 256 + kk);
        float4 a1 = *(const float4*)(X + (m0 + lm) * 256 + kk + 4);
        bf16x8 a;
        a[0] = (short)f2bf(a0.x); a[1] = (short)f2bf(a0.y);
        a[2] = (short)f2bf(a0.z); a[3] = (short)f2bf(a0.w);
        a[4] = (short)f2bf(a1.x); a[5] = (short)f2bf(a1.y);
        a[6] = (short)f2bf(a1.z); a[7] = (short)f2bf(a1.w);
#pragma unroll
        for (int nt = 0; nt < 4; nt++) {
            bf16x8 b = *(const bf16x8*)(Wt + (n0 + nt * 16 + lm) * 256 + kk);
            acc[nt] = __builtin_amdgcn_mfma_f32_16x16x32_bf16(a, b, acc[nt], 0, 0, 0);
        }
    }
#pragma unroll
    for (int nt = 0; nt < 4; nt++) {
        const int c = n0 + nt * 16 + lm;
        const float bsum = bs[c] + bh[c];
#pragma unroll
        for (int i = 0; i < 4; i++) {
            const int r = m0 + q * 4 + i;
            float v = acc[nt][i] + bsum;
            v = v > 0.f ? v : 0.f;   // relu => h >= +0.0 (u16-monotonic f16 bits)
            hb[r * 256 + c] = __builtin_bit_cast(unsigned short, __float2half(v));
        }
    }
}

// one (edge,node) update, member-skip, 2 scalar ops:
//   s_add_u32 we,we,we  -> SCC = carry = old MSB = membership; shifts too.
//   member (SCC=1): 4 pk ops on v directly. non-member: skip.
#define POOL_STEP(WE, MX0, MX1, MN0, MN1, VX, VY)                          \
    {                                                                      \
        asm("s_add_u32 %[we], %[we], %[we]\n\t"                            \
            "s_cbranch_scc0 Lskip%=\n\t"                                   \
            "v_pk_max_i16 %[mx0], %[mx0], %[vx]\n\t"                       \
            "v_pk_max_i16 %[mx1], %[mx1], %[vy]\n\t"                       \
            "v_pk_min_u16 %[mn0], %[mn0], %[vx]\n\t"                       \
            "v_pk_min_u16 %[mn1], %[mn1], %[vy]\n"                         \
            "Lskip%=:"                                                     \
            : [we] "+s"(WE),                                               \
              [mx0] "+v"(MX0), [mx1] "+v"(MX1),                            \
              [mn0] "+v"(MN0), [mn1] "+v"(MN1)                             \
            : [vx] "v"(VX), [vy] "v"(VY)                                   \
            : "scc");                                                      \
    }

// ---------------------------------------------------------------- pool + score
// Block: 4 edges x one branch, 512 threads = 8 waves; wave wv covers nodes
// [wv*512, +512). grid (1024, 2) = 2048 blocks = 4 blocks/CU x 8 waves =
// 32 waves/CU (round-12 had ~20: issue-bubble-bound). h read directly from
// L2 (global_load_dwordx2, batches of 4; each load serves 4 edges). Member-
// skip POOL_STEP: 2 scalar ops + avg 2 pk per (edge,node).
// Merge: per-wave partials -> LDS (32 KB), one barrier, waves 0-3 reduce
// one edge each over 8 partials, dot + shuffle + sigmoid.
// LDS 34 KB. __launch_bounds__(512, 8) -> 4 blocks/CU.
__launch_bounds__(512, 8)
__global__ void k_pool9(const unsigned short* __restrict__ hAll,
                        const unsigned* __restrict__ packed,
                        const float* __restrict__ Wscore,
                        const float* __restrict__ bscore,
                        float* __restrict__ out) {
    __shared__ __align__(16) unsigned bits[4 * 128];           // 2 KB
    __shared__ __align__(16) unsigned part[8][4][64][4];       // [wv][e][lane][4] = 32 KB

    const int t  = threadIdx.x;
    const int wv = t >> 6;
    const int l  = t & 63;
    const int e0 = blockIdx.x * 4;
    const int br = blockIdx.y;
    const unsigned short* h = hAll + (size_t)br * 4096 * 256;

    // stage mask bits for 4 edges: 512 u32 = 128 uint4
    if (t < 128) ((uint4*)bits)[t] = ((const uint4*)(packed + e0 * 128))[t];
    __syncthreads();

    unsigned mx0[4], mx1[4], mn0[4], mn1[4];
#pragma unroll
    for (int e = 0; e < 4; e++) {
        mx0[e] = 0x80008000u; mx1[e] = 0x80008000u;   // -32768 i16: any member (>=0) wins
        mn0[e] = 0xFFFFFFFFu; mn1[e] = 0xFFFFFFFFu;   // 0xFFFF u16: any member (<=0x7C00) wins
    }

    // wave wv scans nodes [wv*512, +512) in 16 chunks of 32
#pragma unroll 1
    for (int ch = 0; ch < 16; ch++) {
        const int w0 = wv * 16 + ch;
        unsigned we0 = (unsigned)__builtin_amdgcn_readfirstlane((int)bits[0 * 128 + w0]);
        unsigned we1 = (unsigned)__builtin_amdgcn_readfirstlane((int)bits[1 * 128 + w0]);
        unsigned we2 = (unsigned)__builtin_amdgcn_readfirstlane((int)bits[2 * 128 + w0]);
        unsigned we3 = (unsigned)__builtin_amdgcn_readfirstlane((int)bits[3 * 128 + w0]);

        const unsigned short* hp = h + (size_t)(wv * 512 + ch * 32) * 256 + 4 * l;
#pragma unroll
        for (int jj = 0; jj < 8; jj++) {
            uint2 v0 = *(const uint2*)(hp + (jj * 4 + 0) * 256);
            uint2 v1 = *(const uint2*)(hp + (jj * 4 + 1) * 256);
            uint2 v2 = *(const uint2*)(hp + (jj * 4 + 2) * 256);
            uint2 v3 = *(const uint2*)(hp + (jj * 4 + 3) * 256);

            POOL_STEP(we0, mx0[0], mx1[0], mn0[0], mn1[0], v0.x, v0.y);
            POOL_STEP(we1, mx0[1], mx1[1], mn0[1], mn1[1], v0.x, v0.y);
            POOL_STEP(we2, mx0[2], mx1[2], mn0[2], mn1[2], v0.x, v0.y);
            POOL_STEP(we3, mx0[3], mx1[3], mn0[3], mn1[3], v0.x, v0.y);

            POOL_STEP(we0, mx0[0], mx1[0], mn0[0], mn1[0], v1.x, v1.y);
            POOL_STEP(we1, mx0[1], mx1[1], mn0[1], mn1[1], v1.x, v1.y);
            POOL_STEP(we2, mx0[2], mx1[2], mn0[2], mn1[2], v1.x, v1.y);
            POOL_STEP(we3, mx0[3], mx1[3], mn0[3], mn1[3], v1.x, v1.y);

            POOL_STEP(we0, mx0[0], mx1[0], mn0[0], mn1[0], v2.x, v2.y);
            POOL_STEP(we1, mx0[1], mx1[1], mn0[1], mn1[1], v2.x, v2.y);
            POOL_STEP(we2, mx0[2], mx1[2], mn0[2], mn1[2], v2.x, v2.y);
            POOL_STEP(we3, mx0[3], mx1[3], mn0[3], mn1[3], v2.x, v2.y);

            POOL_STEP(we0, mx0[0], mx1[0], mn0[0], mn1[0], v3.x, v3.y);
            POOL_STEP(we1, mx0[1], mx1[1], mn0[1], mn1[1], v3.x, v3.y);
            POOL_STEP(we2, mx0[2], mx1[2], mn0[2], mn1[2], v3.x, v3.y);
            POOL_STEP(we3, mx0[3], mx1[3], mn0[3], mn1[3], v3.x, v3.y);
        }
    }

    // write per-wave partials to LDS
#pragma unroll
    for (int e = 0; e < 4; e++) {
        uint4 p; p.x = mx0[e]; p.y = mx1[e]; p.z = mn0[e]; p.w = mn1[e];
        *(uint4*)&part[wv][e][l][0] = p;
    }
    __syncthreads();

    // waves 0-3: reduce edge wv across the 8 node-slice partials
    if (wv < 4) {
        unsigned rmx0 = 0x80008000u, rmx1 = 0x80008000u;
        unsigned rmn0 = 0xFFFFFFFFu, rmn1 = 0xFFFFFFFFu;
#pragma unroll
        for (int w2 = 0; w2 < 8; w2++) {
            uint4 p = *(const uint4*)&part[w2][wv][l][0];
            rmx0 = pkmax_i16(rmx0, p.x);  rmx1 = pkmax_i16(rmx1, p.y);
            rmn0 = pkmin_u16(rmn0, p.z);  rmn1 = pkmin_u16(rmn1, p.w);
        }

        float4 wsv = *(const float4*)(Wscore + 4 * l);
        const float bsc = *bscore;
        float s = (f16u_to_f(rmx0)       - f16u_to_f(rmn0))       * wsv.x
                + (f16u_to_f(rmx0 >> 16) - f16u_to_f(rmn0 >> 16)) * wsv.y
                + (f16u_to_f(rmx1)       - f16u_to_f(rmn1))       * wsv.z
                + (f16u_to_f(rmx1 >> 16) - f16u_to_f(rmn1 >> 16)) * wsv.w;
#pragma unroll
        for (int off = 32; off; off >>= 1) s += __shfl_xor(s, off);
        if (l == 0)
            out[br * 4096 + e0 + wv] = 1.f / (1.f + __expf(-(s + bsc)));
    }
}

// ---------------------------------------------------------------- launch
extern "C" void kernel_launch(void* const* d_in, const int* in_sizes, int n_in,
                              void* d_out, int out_size, void* d_ws, size_t ws_size,
                              hipStream_t stream) {
    const float* pf  = (const float*)d_in[0];
    const float* pm  = (const float*)d_in[1];
    const float* nf  = (const float*)d_in[2];
    const float* nm  = (const float*)d_in[3];
    const int*   msk = (const int*)d_in[4];
    const float* Wsf = (const float*)d_in[5];
    const float* bsf = (const float*)d_in[6];
    const float* Whp = (const float*)d_in[7];
    const float* bhp = (const float*)d_in[8];
    const float* Wsc = (const float*)d_in[9];
    const float* bsc = (const float*)d_in[10];
    float* out = (float*)d_out;

    char* ws = (char*)d_ws;
    unsigned short* hbuf = (unsigned short*)ws;                                   // 4 MB
    unsigned short* Wts  = (unsigned short*)(ws + 4u * 1024 * 1024);              // 128 KB
    unsigned short* Wth  = Wts + 256 * 256;                                       // 128 KB
    unsigned*       pck  = (unsigned*)(ws + 4u * 1024 * 1024 + 512u * 1024);      // 2 MB

    k_transpose<<<dim3(256, 2), 256, 0, stream>>>(Wsf, Whp, Wts, Wth);
    k_pack_mask<<<2048, 256, 0, stream>>>(msk, pck);
    k_gemm_relu<<<dim3(64, 4, 2), 256, 0, stream>>>(pf, pm, nf, nm, Wts, Wth, bsf, bhp, hbuf);
    k_pool9<<<dim3(1024, 2), 512, 0, stream>>>(hbuf, pck, Wsc, bsc, out);
}

// Round 14
// 282.116 us; speedup vs baseline: 2.0744x; 1.3462x over previous
//
#include <hip/hip_runtime.h>
#include <hip/hip_bf16.h>
#include <hip/hip_fp16.h>

// N=4096 nodes, E=4096 hyperedges, F=256, H=256. All float tensors f32;
// batch_mask int32. out = 8192 f32: [pos_score | neg_score].

typedef short bf16x8 __attribute__((ext_vector_type(8)));
typedef float f32x4 __attribute__((ext_vector_type(4)));
typedef short s16x2 __attribute__((ext_vector_type(2)));
typedef unsigned short u16x2 __attribute__((ext_vector_type(2)));

static __device__ __forceinline__ unsigned short f2bf(float f) {
    __hip_bfloat16 b = __float2bfloat16(f);
    return __builtin_bit_cast(unsigned short, b);
}
static __device__ __forceinline__ float f16u_to_f(unsigned u) {
    __half h = __builtin_bit_cast(__half, (unsigned short)(u & 0xffffu));
    return __half2float(h);
}
static __device__ __forceinline__ unsigned pkmax_i16(unsigned a, unsigned b) {
    s16x2 r = __builtin_elementwise_max(__builtin_bit_cast(s16x2, a), __builtin_bit_cast(s16x2, b));
    return __builtin_bit_cast(unsigned, r);
}
static __device__ __forceinline__ unsigned pkmin_u16(unsigned a, unsigned b) {
    u16x2 r = __builtin_elementwise_min(__builtin_bit_cast(u16x2, a), __builtin_bit_cast(u16x2, b));
    return __builtin_bit_cast(unsigned, r);
}

// ---------------------------------------------------------------- transpose W (f32 -> bf16)
__global__ void k_transpose(const float* __restrict__ Ws, const float* __restrict__ Wh,
                            unsigned short* __restrict__ Wts, unsigned short* __restrict__ Wth) {
    int k = blockIdx.x;
    int n = threadIdx.x;
    const float* W     = blockIdx.y ? Wh : Ws;
    unsigned short* Wt = blockIdx.y ? Wth : Wts;
    Wt[n * 256 + k] = f2bf(W[k * 256 + n]);
}

// ---------------------------------------------------------------- pack mask -> bitwords
// NON-inverted, MSB-first: bit (31-j) of packed[e][w] = mask[e][w*32+j].
// Membership test for node idx: (int)(word << (idx&31)) < 0.
__global__ void k_pack_mask(const int* __restrict__ mask, unsigned* __restrict__ packed) {
    int w = blockIdx.x * 256 + threadIdx.x;
    const int* p = mask + (size_t)w * 32;
    unsigned word = 0;
#pragma unroll
    for (int j = 0; j < 32; j += 4) {
        int4 m = *(const int4*)(p + j);
        word |= (m.x != 0 ? (1u << (31 - j)) : 0u)
              | (m.y != 0 ? (1u << (30 - j)) : 0u)
              | (m.z != 0 ? (1u << (29 - j)) : 0u)
              | (m.w != 0 ? (1u << (28 - j)) : 0u);
    }
    packed[w] = word;
}

// ---------------------------------------------------------------- GEMM + relu -> f16 h
__launch_bounds__(256)
__global__ void k_gemm_relu(const float* __restrict__ pXf, const float* __restrict__ pXm,
                            const float* __restrict__ nXf, const float* __restrict__ nXm,
                            const unsigned short* __restrict__ Wts, const unsigned short* __restrict__ Wth,
                            const float* __restrict__ bs,  const float* __restrict__ bh,
                            unsigned short* __restrict__ hAll /* f16 [2][4096][256] */) {
    const int t  = threadIdx.x;
    const int wv = t >> 6;
    const int l  = t & 63;
    const int lm = l & 15;
    const int q  = l >> 4;
    const int bz = blockIdx.z;
    const float* Xf = bz ? nXf : pXf;
    const float* Xm = bz ? nXm : pXm;
    unsigned short* hb = hAll + (size_t)bz * 4096 * 256;

    const int m0 = blockIdx.x * 64 + wv * 16;
    const int n0 = blockIdx.y * 64;

    f32x4 acc[4] = {};
#pragma unroll
    for (int ks = 0; ks < 512; ks += 32) {
        const float* X           = (ks < 256) ? Xf : Xm;
        const unsigned short* Wt = (ks < 256) ? Wts : Wth;
        const int kk = (ks & 255) + q * 8;
        float4 a0 = *(const float4*)(X + (m0 + lm) * 256 + kk);
        float4 a1 = *(const float4*)(X + (m0 + lm) * 256 + kk + 4);
        bf16x8 a;
        a[0] = (short)f2bf(a0.x); a[1] = (short)f2bf(a0.y);
        a[2] = (short)f2bf(a0.z); a[3] = (short)f2bf(a0.w);
        a[4] = (short)f2bf(a1.x); a[5] = (short)f2bf(a1.y);
        a[6] = (short)f2bf(a1.z); a[7] = (short)f2bf(a1.w);
#pragma unroll
        for (int nt = 0; nt < 4; nt++) {
            bf16x8 b = *(const bf16x8*)(Wt + (n0 + nt * 16 + lm) * 256 + kk);
            acc[nt] = __builtin_amdgcn_mfma_f32_16x16x32_bf16(a, b, acc[nt], 0, 0, 0);
        }
    }
#pragma unroll
    for (int nt = 0; nt < 4; nt++) {
        const int c = n0 + nt * 16 + lm;
        const float bsum = bs[c] + bh[c];
#pragma unroll
        for (int i = 0; i < 4; i++) {
            const int r = m0 + q * 4 + i;
            float v = acc[nt][i] + bsum;
            v = v > 0.f ? v : 0.f;   // relu => h >= +0.0 (u16-monotonic f16 bits)
            hb[r * 256 + c] = __builtin_bit_cast(unsigned short, __float2half(v));
        }
    }
}

// ---------------------------------------------------------------- h transpose -> hT [2][256][4096]
// 64x64 LDS tile (unsigned elems, pad 65 -> conflict-free both phases).
// grid (64, 4, 2), block 256.
__global__ void k_transposeH(const unsigned short* __restrict__ h, unsigned short* __restrict__ hT) {
    __shared__ unsigned tile[64][65];
    const int r0 = blockIdx.x * 64, c0 = blockIdx.y * 64, br = blockIdx.z;
    const unsigned short* src = h + (size_t)br * 4096 * 256;
    unsigned short* dst = hT + (size_t)br * 256 * 4096;
    const int t = threadIdx.x;
#pragma unroll
    for (int m = 0; m < 16; m++) {
        int li = t + m * 256; int r = li >> 6, c = li & 63;
        tile[r][c] = src[(size_t)(r0 + r) * 256 + c0 + c];
    }
    __syncthreads();
#pragma unroll
    for (int m = 0; m < 16; m++) {
        int li = t + m * 256; int c = li >> 6, r = li & 63;
        dst[(size_t)(c0 + c) * 4096 + r0 + r] = (unsigned short)tile[r][c];
    }
}

// ---------------------------------------------------------------- per-column bitonic sort
// One block per (col, branch). keys = (f16bits << 16) | idx, ascending u32
// (h >= 0 -> value-monotonic; ties by idx, deterministic). Writes full
// sortedAsc (fallback path) + top16/bot16 in TRANSPOSED [p][c] layout for
// conflict-free LDS gathers in the probe kernel. grid (256, 2), block 256.
__launch_bounds__(256)
__global__ void k_sort(const unsigned short* __restrict__ hT,
                       unsigned* __restrict__ sortedAsc,
                       unsigned* __restrict__ topkG, unsigned* __restrict__ botkG) {
    __shared__ unsigned key[4096];   // 16 KB
    const int c = blockIdx.x, br = blockIdx.y, t = threadIdx.x;
    const unsigned short* src = hT + (size_t)(br * 256 + c) * 4096;
#pragma unroll
    for (int m = 0; m < 16; m++) {
        int i = t + m * 256;
        key[i] = ((unsigned)src[i] << 16) | (unsigned)i;
    }
    __syncthreads();
    for (int k = 2; k <= 4096; k <<= 1) {
        for (int j = k >> 1; j > 0; j >>= 1) {
#pragma unroll
            for (int m = 0; m < 16; m++) {
                int i = t + m * 256;
                int ixj = i ^ j;
                if (ixj > i) {
                    unsigned a = key[i], b = key[ixj];
                    bool up = ((i & k) == 0);
                    if ((a > b) == up) { key[i] = b; key[ixj] = a; }
                }
            }
            __syncthreads();
        }
    }
    unsigned* outp = sortedAsc + (size_t)(br * 256 + c) * 4096;
#pragma unroll
    for (int m = 0; m < 16; m++) { int i = t + m * 256; outp[i] = key[i]; }
    if (t < 16) {
        topkG[(br * 16 + t) * 256 + c] = key[4095 - t];   // descending from max
        botkG[(br * 16 + t) * 256 + c] = key[t];          // ascending from min
    }
}

// ---------------------------------------------------------------- probe + score
// Block: 16 edges x one branch; 4 waves x 4 edges. Lane l covers cols
// c = l + 64*sl (stride-1 LDS gathers). Per (edge,col): masked max = first
// member probing sorted-descending (top16 in LDS, then global sortedAsc --
// exact unbounded fallback); min symmetric. Expected ~2 probes/(edge,col)
// (mask ~50% dense; diagonal guarantees termination).
// LDS 40 KB. grid (256, 2), block 256.
__launch_bounds__(256)
__global__ void k_probe(const unsigned* __restrict__ sortedAsc,
                        const unsigned* __restrict__ topkG,
                        const unsigned* __restrict__ botkG,
                        const unsigned* __restrict__ packed,
                        const float* __restrict__ Wscore,
                        const float* __restrict__ bscore,
                        float* __restrict__ out) {
    __shared__ __align__(16) unsigned topkL[16 * 256];   // [p][c] 16 KB
    __shared__ __align__(16) unsigned botkL[16 * 256];   // [p][c] 16 KB
    __shared__ __align__(16) unsigned bitsL[16 * 128];   // 16 edges x 128 words, 8 KB

    const int t  = threadIdx.x;
    const int wv = t >> 6;
    const int l  = t & 63;
    const int e0 = blockIdx.x * 16;
    const int br = blockIdx.y;

    {   // stage top/bot-16 (coalesced; per-branch shared data) + edge masks
        const uint4* ts = (const uint4*)(topkG + br * 4096);
        const uint4* bs2 = (const uint4*)(botkG + br * 4096);
#pragma unroll
        for (int m = 0; m < 4; m++) {
            ((uint4*)topkL)[t + m * 256] = ts[t + m * 256];
            ((uint4*)botkL)[t + m * 256] = bs2[t + m * 256];
        }
        ((uint4*)bitsL)[t]       = ((const uint4*)(packed + e0 * 128))[t];
        ((uint4*)bitsL)[t + 256] = ((const uint4*)(packed + e0 * 128))[t + 256];
    }
    __syncthreads();

    const float bsc = *bscore;
    float wsv[4];
#pragma unroll
    for (int sl = 0; sl < 4; sl++) wsv[sl] = Wscore[l + 64 * sl];

#pragma unroll 1
    for (int k = 0; k < 4; k++) {
        const int e = wv * 4 + k;
        const unsigned* mk = &bitsL[e * 128];
        float s = 0.f;
#pragma unroll
        for (int sl = 0; sl < 4; sl++) {
            const int c = l + 64 * sl;
            const unsigned* gs = sortedAsc + (size_t)(br * 256 + c) * 4096;
            float vmax = 0.f, vmin = 0.f;
#pragma unroll 1
            for (int p = 0; p < 4096; p++) {
                unsigned key = (p < 16) ? topkL[p * 256 + c] : gs[4095 - p];
                unsigned idx = key & 4095u;
                if ((int)(mk[idx >> 5] << (idx & 31)) < 0) { vmax = f16u_to_f(key >> 16); break; }
            }
#pragma unroll 1
            for (int p = 0; p < 4096; p++) {
                unsigned key = (p < 16) ? botkL[p * 256 + c] : gs[p];
                unsigned idx = key & 4095u;
                if ((int)(mk[idx >> 5] << (idx & 31)) < 0) { vmin = f16u_to_f(key >> 16); break; }
            }
            s += (vmax - vmin) * wsv[sl];
        }
#pragma unroll
        for (int off = 32; off; off >>= 1) s += __shfl_xor(s, off);
        if (l == 0)
            out[br * 4096 + e0 + e] = 1.f / (1.f + __expf(-(s + bsc)));
    }
}

// ================================================================ fallback
// Round-13 proven pool (brute-force member-skip scan) for small-ws safety.
#define POOL_STEP(WE, MX0, MX1, MN0, MN1, VX, VY)                          \
    {                                                                      \
        asm("s_add_u32 %[we], %[we], %[we]\n\t"                            \
            "s_cbranch_scc0 Lskip%=\n\t"                                   \
            "v_pk_max_i16 %[mx0], %[mx0], %[vx]\n\t"                       \
            "v_pk_max_i16 %[mx1], %[mx1], %[vy]\n\t"                       \
            "v_pk_min_u16 %[mn0], %[mn0], %[vx]\n\t"                       \
            "v_pk_min_u16 %[mn1], %[mn1], %[vy]\n"                         \
            "Lskip%=:"                                                     \
            : [we] "+s"(WE),                                               \
              [mx0] "+v"(MX0), [mx1] "+v"(MX1),                            \
              [mn0] "+v"(MN0), [mn1] "+v"(MN1)                             \
            : [vx] "v"(VX), [vy] "v"(VY)                                   \
            : "scc");                                                      \
    }

__launch_bounds__(512, 8)
__global__ void k_pool9(const unsigned short* __restrict__ hAll,
                        const unsigned* __restrict__ packed,
                        const float* __restrict__ Wscore,
                        const float* __restrict__ bscore,
                        float* __restrict__ out) {
    __shared__ __align__(16) unsigned bits[4 * 128];
    __shared__ __align__(16) unsigned part[8][4][64][4];

    const int t  = threadIdx.x;
    const int wv = t >> 6;
    const int l  = t & 63;
    const int e0 = blockIdx.x * 4;
    const int br = blockIdx.y;
    const unsigned short* h = hAll + (size_t)br * 4096 * 256;

    if (t < 128) ((uint4*)bits)[t] = ((const uint4*)(packed + e0 * 128))[t];
    __syncthreads();

    unsigned mx0[4], mx1[4], mn0[4], mn1[4];
#pragma unroll
    for (int e = 0; e < 4; e++) {
        mx0[e] = 0x80008000u; mx1[e] = 0x80008000u;
        mn0[e] = 0xFFFFFFFFu; mn1[e] = 0xFFFFFFFFu;
    }

#pragma unroll 1
    for (int ch = 0; ch < 16; ch++) {
        const int w0 = wv * 16 + ch;
        unsigned we0 = (unsigned)__builtin_amdgcn_readfirstlane((int)bits[0 * 128 + w0]);
        unsigned we1 = (unsigned)__builtin_amdgcn_readfirstlane((int)bits[1 * 128 + w0]);
        unsigned we2 = (unsigned)__builtin_amdgcn_readfirstlane((int)bits[2 * 128 + w0]);
        unsigned we3 = (unsigned)__builtin_amdgcn_readfirstlane((int)bits[3 * 128 + w0]);

        const unsigned short* hp = h + (size_t)(wv * 512 + ch * 32) * 256 + 4 * l;
#pragma unroll
        for (int jj = 0; jj < 8; jj++) {
            uint2 v0 = *(const uint2*)(hp + (jj * 4 + 0) * 256);
            uint2 v1 = *(const uint2*)(hp + (jj * 4 + 1) * 256);
            uint2 v2 = *(const uint2*)(hp + (jj * 4 + 2) * 256);
            uint2 v3 = *(const uint2*)(hp + (jj * 4 + 3) * 256);

            POOL_STEP(we0, mx0[0], mx1[0], mn0[0], mn1[0], v0.x, v0.y);
            POOL_STEP(we1, mx0[1], mx1[1], mn0[1], mn1[1], v0.x, v0.y);
            POOL_STEP(we2, mx0[2], mx1[2], mn0[2], mn1[2], v0.x, v0.y);
            POOL_STEP(we3, mx0[3], mx1[3], mn0[3], mn1[3], v0.x, v0.y);
            POOL_STEP(we0, mx0[0], mx1[0], mn0[0], mn1[0], v1.x, v1.y);
            POOL_STEP(we1, mx0[1], mx1[1], mn0[1], mn1[1], v1.x, v1.y);
            POOL_STEP(we2, mx0[2], mx1[2], mn0[2], mn1[2], v1.x, v1.y);
            POOL_STEP(we3, mx0[3], mx1[3], mn0[3], mn1[3], v1.x, v1.y);
            POOL_STEP(we0, mx0[0], mx1[0], mn0[0], mn1[0], v2.x, v2.y);
            POOL_STEP(we1, mx0[1], mx1[1], mn0[1], mn1[1], v2.x, v2.y);
            POOL_STEP(we2, mx0[2], mx1[2], mn0[2], mn1[2], v2.x, v2.y);
            POOL_STEP(we3, mx0[3], mx1[3], mn0[3], mn1[3], v2.x, v2.y);
            POOL_STEP(we0, mx0[0], mx1[0], mn0[0], mn1[0], v3.x, v3.y);
            POOL_STEP(we1, mx0[1], mx1[1], mn0[1], mn1[1], v3.x, v3.y);
            POOL_STEP(we2, mx0[2], mx1[2], mn0[2], mn1[2], v3.x, v3.y);
            POOL_STEP(we3, mx0[3], mx1[3], mn0[3], mn1[3], v3.x, v3.y);
        }
    }

#pragma unroll
    for (int e = 0; e < 4; e++) {
        uint4 p; p.x = mx0[e]; p.y = mx1[e]; p.z = mn0[e]; p.w = mn1[e];
        *(uint4*)&part[wv][e][l][0] = p;
    }
    __syncthreads();

    if (wv < 4) {
        unsigned rmx0 = 0x80008000u, rmx1 = 0x80008000u;
        unsigned rmn0 = 0xFFFFFFFFu, rmn1 = 0xFFFFFFFFu;
#pragma unroll
        for (int w2 = 0; w2 < 8; w2++) {
            uint4 p = *(const uint4*)&part[w2][wv][l][0];
            rmx0 = pkmax_i16(rmx0, p.x);  rmx1 = pkmax_i16(rmx1, p.y);
            rmn0 = pkmin_u16(rmn0, p.z);  rmn1 = pkmin_u16(rmn1, p.w);
        }
        float4 wsv = *(const float4*)(Wscore + 4 * l);
        const float bsc = *bscore;
        float s = (f16u_to_f(rmx0)       - f16u_to_f(rmn0))       * wsv.x
                + (f16u_to_f(rmx0 >> 16) - f16u_to_f(rmn0 >> 16)) * wsv.y
                + (f16u_to_f(rmx1)       - f16u_to_f(rmn1))       * wsv.z
                + (f16u_to_f(rmx1 >> 16) - f16u_to_f(rmn1 >> 16)) * wsv.w;
#pragma unroll
        for (int off = 32; off; off >>= 1) s += __shfl_xor(s, off);
        if (l == 0)
            out[br * 4096 + e0 + wv] = 1.f / (1.f + __expf(-(s + bsc)));
    }
}

// ---------------------------------------------------------------- launch
extern "C" void kernel_launch(void* const* d_in, const int* in_sizes, int n_in,
                              void* d_out, int out_size, void* d_ws, size_t ws_size,
                              hipStream_t stream) {
    const float* pf  = (const float*)d_in[0];
    const float* pm  = (const float*)d_in[1];
    const float* nf  = (const float*)d_in[2];
    const float* nm  = (const float*)d_in[3];
    const int*   msk = (const int*)d_in[4];
    const float* Wsf = (const float*)d_in[5];
    const float* bsf = (const float*)d_in[6];
    const float* Whp = (const float*)d_in[7];
    const float* bhp = (const float*)d_in[8];
    const float* Wsc = (const float*)d_in[9];
    const float* bsc = (const float*)d_in[10];
    float* out = (float*)d_out;

    char* ws = (char*)d_ws;
    const size_t MB = 1024u * 1024u;
    unsigned short* hbuf  = (unsigned short*)(ws);                 // 4 MB  [2][4096][256]
    unsigned short* hT    = (unsigned short*)(ws + 4 * MB);        // 4 MB  [2][256][4096]
    unsigned*       srt   = (unsigned*)(ws + 8 * MB);              // 8 MB  [2][256][4096]
    unsigned*       pck   = (unsigned*)(ws + 16 * MB);             // 2 MB  [4096][128]
    unsigned short* Wts   = (unsigned short*)(ws + 18 * MB);       // 128 KB
    unsigned short* Wth   = Wts + 256 * 256;                       // 128 KB
    unsigned*       topkG = (unsigned*)(ws + 18 * MB + 256 * 1024);          // 32 KB
    unsigned*       botkG = (unsigned*)(ws + 18 * MB + 256 * 1024 + 32768);  // 32 KB
    const size_t need = 18 * MB + 256 * 1024 + 2 * 32768;

    k_transpose<<<dim3(256, 2), 256, 0, stream>>>(Wsf, Whp, Wts, Wth);
    k_pack_mask<<<2048, 256, 0, stream>>>(msk, pck);
    k_gemm_relu<<<dim3(64, 4, 2), 256, 0, stream>>>(pf, pm, nf, nm, Wts, Wth, bsf, bhp, hbuf);

    if (ws_size >= need) {
        k_transposeH<<<dim3(64, 4, 2), 256, 0, stream>>>(hbuf, hT);
        k_sort<<<dim3(256, 2), 256, 0, stream>>>(hT, srt, topkG, botkG);
        k_probe<<<dim3(256, 2), 256, 0, stream>>>(srt, topkG, botkG, pck, Wsc, bsc, out);
    } else {
        // small-ws fallback: round-13 brute-force pool (fits in 8.6 MB)
        k_pool9<<<dim3(1024, 2), 512, 0, stream>>>(hbuf, pck, Wsc, bsc, out);
    }
}

// Round 15
// 211.455 us; speedup vs baseline: 2.7676x; 1.3342x over previous
//
#include <hip/hip_runtime.h>
#include <hip/hip_bf16.h>
#include <hip/hip_fp16.h>

// N=4096 nodes, E=4096 hyperedges, F=256, H=256. All float tensors f32;
// batch_mask int32. out = 8192 f32: [pos_score | neg_score].

typedef short bf16x8 __attribute__((ext_vector_type(8)));
typedef float f32x4 __attribute__((ext_vector_type(4)));
typedef short s16x2 __attribute__((ext_vector_type(2)));
typedef unsigned short u16x2 __attribute__((ext_vector_type(2)));

static __device__ __forceinline__ unsigned short f2bf(float f) {
    __hip_bfloat16 b = __float2bfloat16(f);
    return __builtin_bit_cast(unsigned short, b);
}
static __device__ __forceinline__ float f16u_to_f(unsigned u) {
    __half h = __builtin_bit_cast(__half, (unsigned short)(u & 0xffffu));
    return __half2float(h);
}
static __device__ __forceinline__ unsigned pkmax_i16(unsigned a, unsigned b) {
    s16x2 r = __builtin_elementwise_max(__builtin_bit_cast(s16x2, a), __builtin_bit_cast(s16x2, b));
    return __builtin_bit_cast(unsigned, r);
}
static __device__ __forceinline__ unsigned pkmin_u16(unsigned a, unsigned b) {
    u16x2 r = __builtin_elementwise_min(__builtin_bit_cast(u16x2, a), __builtin_bit_cast(u16x2, b));
    return __builtin_bit_cast(unsigned, r);
}

// ---------------------------------------------------------------- transpose W (f32 -> bf16)
__global__ void k_transpose(const float* __restrict__ Ws, const float* __restrict__ Wh,
                            unsigned short* __restrict__ Wts, unsigned short* __restrict__ Wth) {
    int k = blockIdx.x;
    int n = threadIdx.x;
    const float* W     = blockIdx.y ? Wh : Ws;
    unsigned short* Wt = blockIdx.y ? Wth : Wts;
    Wt[n * 256 + k] = f2bf(W[k * 256 + n]);
}

// ---------------------------------------------------------------- pack mask -> bitwords
// NON-inverted, MSB-first: bit (31-j) of packed[e][w] = mask[e][w*32+j].
// Membership test for node idx: (int)(word << (idx&31)) < 0.
__global__ void k_pack_mask(const int* __restrict__ mask, unsigned* __restrict__ packed) {
    int w = blockIdx.x * 256 + threadIdx.x;
    const int* p = mask + (size_t)w * 32;
    unsigned word = 0;
#pragma unroll
    for (int j = 0; j < 32; j += 4) {
        int4 m = *(const int4*)(p + j);
        word |= (m.x != 0 ? (1u << (31 - j)) : 0u)
              | (m.y != 0 ? (1u << (30 - j)) : 0u)
              | (m.z != 0 ? (1u << (29 - j)) : 0u)
              | (m.w != 0 ? (1u << (28 - j)) : 0u);
    }
    packed[w] = word;
}

// ---------------------------------------------------------------- GEMM + relu -> f16 h
__launch_bounds__(256)
__global__ void k_gemm_relu(const float* __restrict__ pXf, const float* __restrict__ pXm,
                            const float* __restrict__ nXf, const float* __restrict__ nXm,
                            const unsigned short* __restrict__ Wts, const unsigned short* __restrict__ Wth,
                            const float* __restrict__ bs,  const float* __restrict__ bh,
                            unsigned short* __restrict__ hAll /* f16 [2][4096][256] */) {
    const int t  = threadIdx.x;
    const int wv = t >> 6;
    const int l  = t & 63;
    const int lm = l & 15;
    const int q  = l >> 4;
    const int bz = blockIdx.z;
    const float* Xf = bz ? nXf : pXf;
    const float* Xm = bz ? nXm : pXm;
    unsigned short* hb = hAll + (size_t)bz * 4096 * 256;

    const int m0 = blockIdx.x * 64 + wv * 16;
    const int n0 = blockIdx.y * 64;

    f32x4 acc[4] = {};
#pragma unroll
    for (int ks = 0; ks < 512; ks += 32) {
        const float* X           = (ks < 256) ? Xf : Xm;
        const unsigned short* Wt = (ks < 256) ? Wts : Wth;
        const int kk = (ks & 255) + q * 8;
        float4 a0 = *(const float4*)(X + (m0 + lm) * 256 + kk);
        float4 a1 = *(const float4*)(X + (m0 + lm) * 256 + kk + 4);
        bf16x8 a;
        a[0] = (short)f2bf(a0.x); a[1] = (short)f2bf(a0.y);
        a[2] = (short)f2bf(a0.z); a[3] = (short)f2bf(a0.w);
        a[4] = (short)f2bf(a1.x); a[5] = (short)f2bf(a1.y);
        a[6] = (short)f2bf(a1.z); a[7] = (short)f2bf(a1.w);
#pragma unroll
        for (int nt = 0; nt < 4; nt++) {
            bf16x8 b = *(const bf16x8*)(Wt + (n0 + nt * 16 + lm) * 256 + kk);
            acc[nt] = __builtin_amdgcn_mfma_f32_16x16x32_bf16(a, b, acc[nt], 0, 0, 0);
        }
    }
#pragma unroll
    for (int nt = 0; nt < 4; nt++) {
        const int c = n0 + nt * 16 + lm;
        const float bsum = bs[c] + bh[c];
#pragma unroll
        for (int i = 0; i < 4; i++) {
            const int r = m0 + q * 4 + i;
            float v = acc[nt][i] + bsum;
            v = v > 0.f ? v : 0.f;   // relu => h >= +0.0 (u16-monotonic f16 bits)
            hb[r * 256 + c] = __builtin_bit_cast(unsigned short, __float2half(v));
        }
    }
}

// ---------------------------------------------------------------- h transpose -> hT [2][256][4096]
__global__ void k_transposeH(const unsigned short* __restrict__ h, unsigned short* __restrict__ hT) {
    __shared__ unsigned tile[64][65];
    const int r0 = blockIdx.x * 64, c0 = blockIdx.y * 64, br = blockIdx.z;
    const unsigned short* src = h + (size_t)br * 4096 * 256;
    unsigned short* dst = hT + (size_t)br * 256 * 4096;
    const int t = threadIdx.x;
#pragma unroll
    for (int m = 0; m < 16; m++) {
        int li = t + m * 256; int r = li >> 6, c = li & 63;
        tile[r][c] = src[(size_t)(r0 + r) * 256 + c0 + c];
    }
    __syncthreads();
#pragma unroll
    for (int m = 0; m < 16; m++) {
        int li = t + m * 256; int c = li >> 6, r = li & 63;
        dst[(size_t)(c0 + c) * 4096 + r0 + r] = (unsigned short)tile[r][c];
    }
}

// ---------------------------------------------------------------- per-column LSD radix sort
// One block per (col, branch). keys = (f16bits << 16) | idx; sort key = the
// 16-bit value field (h >= 0 -> u16-monotonic), 4 passes x 4-bit digits.
// Thread t owns items [t*16, t*16+16) -> per-thread histograms + flattened
// exclusive scan give STABLE deterministic ranks, no atomics. Ties carry
// equal values, so tie order cannot change probe results.
// Replaces the round-14 bitonic sort (78 barrier phases, 103 us: barrier-
// bound at 15% VALUBusy). ~17 barriers total. LDS 40.2 KB -> 4 blocks/CU.
// grid (256, 2), block 256.
__launch_bounds__(256)
__global__ void k_sort(const unsigned short* __restrict__ hT,
                       unsigned* __restrict__ sortedAsc,
                       unsigned* __restrict__ topkG, unsigned* __restrict__ botkG) {
    __shared__ unsigned arrA[4096];              // 16 KB
    __shared__ unsigned arrB[4096];              // 16 KB
    __shared__ unsigned short hist[16 * 256];    // 8 KB, flattened [bin*256 + thread]
    __shared__ unsigned wsum[4];

    const int c = blockIdx.x, br = blockIdx.y, t = threadIdx.x;
    const int wv = t >> 6, l = t & 63;
    const unsigned short* src = hT + (size_t)(br * 256 + c) * 4096;

    {   // load 16 consecutive u16 per thread (32 B = 2 x uint4), build keys
        uint4 a = ((const uint4*)src)[t * 2];
        uint4 b = ((const uint4*)src)[t * 2 + 1];
        unsigned base = t * 16;
        unsigned w[8] = {a.x, a.y, a.z, a.w, b.x, b.y, b.z, b.w};
#pragma unroll
        for (int m = 0; m < 8; m++) {
            arrA[base + 2 * m]     = ((w[m] & 0xFFFFu) << 16) | (base + 2 * m);
            arrA[base + 2 * m + 1] = (w[m] & 0xFFFF0000u)     | (base + 2 * m + 1);
        }
    }
    __syncthreads();

    unsigned* A = arrA;
    unsigned* B = arrB;
#pragma unroll
    for (int pass = 0; pass < 4; pass++) {
        const int sh = 16 + pass * 4;
        // 1. per-thread histogram over its 16 items (kept in registers)
        unsigned keys[16];
        unsigned short cnt[16];
#pragma unroll
        for (int b = 0; b < 16; b++) cnt[b] = 0;
#pragma unroll
        for (int m = 0; m < 16; m++) {
            keys[m] = A[t * 16 + m];
            cnt[(keys[m] >> sh) & 15u]++;
        }
#pragma unroll
        for (int b = 0; b < 16; b++) hist[b * 256 + t] = cnt[b];
        __syncthreads();

        // 2. exclusive scan of the flattened 4096-entry histogram
        unsigned loc[16];
        unsigned sum = 0;
#pragma unroll
        for (int m = 0; m < 16; m++) { loc[m] = sum; sum += hist[t * 16 + m]; }
        unsigned ws = sum;
#pragma unroll
        for (int off = 1; off < 64; off <<= 1) {
            unsigned n = __shfl_up(ws, off);
            if (l >= off) ws += n;
        }
        if (l == 63) wsum[wv] = ws;
        __syncthreads();
        unsigned wbase = 0;
#pragma unroll
        for (int w2 = 0; w2 < 4; w2++) if (w2 < wv) wbase += wsum[w2];
        const unsigned ex = wbase + ws - sum;
#pragma unroll
        for (int m = 0; m < 16; m++) hist[t * 16 + m] = (unsigned short)(ex + loc[m]);
        __syncthreads();

        // 3. deterministic scatter via register offsets
        unsigned offs[16];
#pragma unroll
        for (int b = 0; b < 16; b++) offs[b] = hist[b * 256 + t];
#pragma unroll
        for (int m = 0; m < 16; m++) {
            unsigned b = (keys[m] >> sh) & 15u;
            B[offs[b]++] = keys[m];
        }
        __syncthreads();
        unsigned* tmp = A; A = B; B = tmp;
    }
    // 4 passes (even) -> result back in arrA, ascending by value

    unsigned* outp = sortedAsc + (size_t)(br * 256 + c) * 4096;
#pragma unroll
    for (int m = 0; m < 16; m++) { int i = t + m * 256; outp[i] = arrA[i]; }
    if (t < 16) {
        topkG[(br * 16 + t) * 256 + c] = arrA[4095 - t];   // descending from max
        botkG[(br * 16 + t) * 256 + c] = arrA[t];          // ascending from min
    }
}

// ---------------------------------------------------------------- probe + score
// Block: 16 edges x one branch; 4 waves x 4 edges. Lane l covers cols
// c = l + 64*sl (stride-1 LDS gathers). Per (edge,col): masked max = first
// member probing sorted-descending (top16 in LDS, then global sortedAsc --
// exact unbounded fallback); min symmetric. Expected ~2 probes/(edge,col).
// LDS 40 KB. grid (256, 2), block 256.
__launch_bounds__(256)
__global__ void k_probe(const unsigned* __restrict__ sortedAsc,
                        const unsigned* __restrict__ topkG,
                        const unsigned* __restrict__ botkG,
                        const unsigned* __restrict__ packed,
                        const float* __restrict__ Wscore,
                        const float* __restrict__ bscore,
                        float* __restrict__ out) {
    __shared__ __align__(16) unsigned topkL[16 * 256];   // [p][c] 16 KB
    __shared__ __align__(16) unsigned botkL[16 * 256];   // [p][c] 16 KB
    __shared__ __align__(16) unsigned bitsL[16 * 128];   // 16 edges x 128 words, 8 KB

    const int t  = threadIdx.x;
    const int wv = t >> 6;
    const int l  = t & 63;
    const int e0 = blockIdx.x * 16;
    const int br = blockIdx.y;

    {
        const uint4* ts  = (const uint4*)(topkG + br * 4096);
        const uint4* bs2 = (const uint4*)(botkG + br * 4096);
#pragma unroll
        for (int m = 0; m < 4; m++) {
            ((uint4*)topkL)[t + m * 256] = ts[t + m * 256];
            ((uint4*)botkL)[t + m * 256] = bs2[t + m * 256];
        }
        ((uint4*)bitsL)[t]       = ((const uint4*)(packed + e0 * 128))[t];
        ((uint4*)bitsL)[t + 256] = ((const uint4*)(packed + e0 * 128))[t + 256];
    }
    __syncthreads();

    const float bsc = *bscore;
    float wsv[4];
#pragma unroll
    for (int sl = 0; sl < 4; sl++) wsv[sl] = Wscore[l + 64 * sl];

#pragma unroll 1
    for (int k = 0; k < 4; k++) {
        const int e = wv * 4 + k;
        const unsigned* mk = &bitsL[e * 128];
        float s = 0.f;
#pragma unroll
        for (int sl = 0; sl < 4; sl++) {
            const int c = l + 64 * sl;
            const unsigned* gs = sortedAsc + (size_t)(br * 256 + c) * 4096;
            float vmax = 0.f, vmin = 0.f;
#pragma unroll 1
            for (int p = 0; p < 4096; p++) {
                unsigned key = (p < 16) ? topkL[p * 256 + c] : gs[4095 - p];
                unsigned idx = key & 4095u;
                if ((int)(mk[idx >> 5] << (idx & 31)) < 0) { vmax = f16u_to_f(key >> 16); break; }
            }
#pragma unroll 1
            for (int p = 0; p < 4096; p++) {
                unsigned key = (p < 16) ? botkL[p * 256 + c] : gs[p];
                unsigned idx = key & 4095u;
                if ((int)(mk[idx >> 5] << (idx & 31)) < 0) { vmin = f16u_to_f(key >> 16); break; }
            }
            s += (vmax - vmin) * wsv[sl];
        }
#pragma unroll
        for (int off = 32; off; off >>= 1) s += __shfl_xor(s, off);
        if (l == 0)
            out[br * 4096 + e0 + e] = 1.f / (1.f + __expf(-(s + bsc)));
    }
}

// ================================================================ fallback
// Round-13 proven pool (brute-force member-skip scan) for small-ws safety.
#define POOL_STEP(WE, MX0, MX1, MN0, MN1, VX, VY)                          \
    {                                                                      \
        asm("s_add_u32 %[we], %[we], %[we]\n\t"                            \
            "s_cbranch_scc0 Lskip%=\n\t"                                   \
            "v_pk_max_i16 %[mx0], %[mx0], %[vx]\n\t"                       \
            "v_pk_max_i16 %[mx1], %[mx1], %[vy]\n\t"                       \
            "v_pk_min_u16 %[mn0], %[mn0], %[vx]\n\t"                       \
            "v_pk_min_u16 %[mn1], %[mn1], %[vy]\n"                         \
            "Lskip%=:"                                                     \
            : [we] "+s"(WE),                                               \
              [mx0] "+v"(MX0), [mx1] "+v"(MX1),                            \
              [mn0] "+v"(MN0), [mn1] "+v"(MN1)                             \
            : [vx] "v"(VX), [vy] "v"(VY)                                   \
            : "scc");                                                      \
    }

__launch_bounds__(512, 8)
__global__ void k_pool9(const unsigned short* __restrict__ hAll,
                        const unsigned* __restrict__ packed,
                        const float* __restrict__ Wscore,
                        const float* __restrict__ bscore,
                        float* __restrict__ out) {
    __shared__ __align__(16) unsigned bits[4 * 128];
    __shared__ __align__(16) unsigned part[8][4][64][4];

    const int t  = threadIdx.x;
    const int wv = t >> 6;
    const int l  = t & 63;
    const int e0 = blockIdx.x * 4;
    const int br = blockIdx.y;
    const unsigned short* h = hAll + (size_t)br * 4096 * 256;

    if (t < 128) ((uint4*)bits)[t] = ((const uint4*)(packed + e0 * 128))[t];
    __syncthreads();

    unsigned mx0[4], mx1[4], mn0[4], mn1[4];
#pragma unroll
    for (int e = 0; e < 4; e++) {
        mx0[e] = 0x80008000u; mx1[e] = 0x80008000u;
        mn0[e] = 0xFFFFFFFFu; mn1[e] = 0xFFFFFFFFu;
    }

#pragma unroll 1
    for (int ch = 0; ch < 16; ch++) {
        const int w0 = wv * 16 + ch;
        unsigned we0 = (unsigned)__builtin_amdgcn_readfirstlane((int)bits[0 * 128 + w0]);
        unsigned we1 = (unsigned)__builtin_amdgcn_readfirstlane((int)bits[1 * 128 + w0]);
        unsigned we2 = (unsigned)__builtin_amdgcn_readfirstlane((int)bits[2 * 128 + w0]);
        unsigned we3 = (unsigned)__builtin_amdgcn_readfirstlane((int)bits[3 * 128 + w0]);

        const unsigned short* hp = h + (size_t)(wv * 512 + ch * 32) * 256 + 4 * l;
#pragma unroll
        for (int jj = 0; jj < 8; jj++) {
            uint2 v0 = *(const uint2*)(hp + (jj * 4 + 0) * 256);
            uint2 v1 = *(const uint2*)(hp + (jj * 4 + 1) * 256);
            uint2 v2 = *(const uint2*)(hp + (jj * 4 + 2) * 256);
            uint2 v3 = *(const uint2*)(hp + (jj * 4 + 3) * 256);

            POOL_STEP(we0, mx0[0], mx1[0], mn0[0], mn1[0], v0.x, v0.y);
            POOL_STEP(we1, mx0[1], mx1[1], mn0[1], mn1[1], v0.x, v0.y);
            POOL_STEP(we2, mx0[2], mx1[2], mn0[2], mn1[2], v0.x, v0.y);
            POOL_STEP(we3, mx0[3], mx1[3], mn0[3], mn1[3], v0.x, v0.y);
            POOL_STEP(we0, mx0[0], mx1[0], mn0[0], mn1[0], v1.x, v1.y);
            POOL_STEP(we1, mx0[1], mx1[1], mn0[1], mn1[1], v1.x, v1.y);
            POOL_STEP(we2, mx0[2], mx1[2], mn0[2], mn1[2], v1.x, v1.y);
            POOL_STEP(we3, mx0[3], mx1[3], mn0[3], mn1[3], v1.x, v1.y);
            POOL_STEP(we0, mx0[0], mx1[0], mn0[0], mn1[0], v2.x, v2.y);
            POOL_STEP(we1, mx0[1], mx1[1], mn0[1], mn1[1], v2.x, v2.y);
            POOL_STEP(we2, mx0[2], mx1[2], mn0[2], mn1[2], v2.x, v2.y);
            POOL_STEP(we3, mx0[3], mx1[3], mn0[3], mn1[3], v2.x, v2.y);
            POOL_STEP(we0, mx0[0], mx1[0], mn0[0], mn1[0], v3.x, v3.y);
            POOL_STEP(we1, mx0[1], mx1[1], mn0[1], mn1[1], v3.x, v3.y);
            POOL_STEP(we2, mx0[2], mx1[2], mn0[2], mn1[2], v3.x, v3.y);
            POOL_STEP(we3, mx0[3], mx1[3], mn0[3], mn1[3], v3.x, v3.y);
        }
    }

#pragma unroll
    for (int e = 0; e < 4; e++) {
        uint4 p; p.x = mx0[e]; p.y = mx1[e]; p.z = mn0[e]; p.w = mn1[e];
        *(uint4*)&part[wv][e][l][0] = p;
    }
    __syncthreads();

    if (wv < 4) {
        unsigned rmx0 = 0x80008000u, rmx1 = 0x80008000u;
        unsigned rmn0 = 0xFFFFFFFFu, rmn1 = 0xFFFFFFFFu;
#pragma unroll
        for (int w2 = 0; w2 < 8; w2++) {
            uint4 p = *(const uint4*)&part[w2][wv][l][0];
            rmx0 = pkmax_i16(rmx0, p.x);  rmx1 = pkmax_i16(rmx1, p.y);
            rmn0 = pkmin_u16(rmn0, p.z);  rmn1 = pkmin_u16(rmn1, p.w);
        }
        float4 wsv = *(const float4*)(Wscore + 4 * l);
        const float bsc = *bscore;
        float s = (f16u_to_f(rmx0)       - f16u_to_f(rmn0))       * wsv.x
                + (f16u_to_f(rmx0 >> 16) - f16u_to_f(rmn0 >> 16)) * wsv.y
                + (f16u_to_f(rmx1)       - f16u_to_f(rmn1))       * wsv.z
                + (f16u_to_f(rmx1 >> 16) - f16u_to_f(rmn1 >> 16)) * wsv.w;
#pragma unroll
        for (int off = 32; off; off >>= 1) s += __shfl_xor(s, off);
        if (l == 0)
            out[br * 4096 + e0 + wv] = 1.f / (1.f + __expf(-(s + bsc)));
    }
}

// ---------------------------------------------------------------- launch
extern "C" void kernel_launch(void* const* d_in, const int* in_sizes, int n_in,
                              void* d_out, int out_size, void* d_ws, size_t ws_size,
                              hipStream_t stream) {
    const float* pf  = (const float*)d_in[0];
    const float* pm  = (const float*)d_in[1];
    const float* nf  = (const float*)d_in[2];
    const float* nm  = (const float*)d_in[3];
    const int*   msk = (const int*)d_in[4];
    const float* Wsf = (const float*)d_in[5];
    const float* bsf = (const float*)d_in[6];
    const float* Whp = (const float*)d_in[7];
    const float* bhp = (const float*)d_in[8];
    const float* Wsc = (const float*)d_in[9];
    const float* bsc = (const float*)d_in[10];
    float* out = (float*)d_out;

    char* ws = (char*)d_ws;
    const size_t MB = 1024u * 1024u;
    unsigned short* hbuf  = (unsigned short*)(ws);                 // 4 MB  [2][4096][256]
    unsigned short* hT    = (unsigned short*)(ws + 4 * MB);        // 4 MB  [2][256][4096]
    unsigned*       srt   = (unsigned*)(ws + 8 * MB);              // 8 MB  [2][256][4096]
    unsigned*       pck   = (unsigned*)(ws + 16 * MB);             // 2 MB  [4096][128]
    unsigned short* Wts   = (unsigned short*)(ws + 18 * MB);       // 128 KB
    unsigned short* Wth   = Wts + 256 * 256;                       // 128 KB
    unsigned*       topkG = (unsigned*)(ws + 18 * MB + 256 * 1024);          // 32 KB
    unsigned*       botkG = (unsigned*)(ws + 18 * MB + 256 * 1024 + 32768);  // 32 KB
    const size_t need = 18 * MB + 256 * 1024 + 2 * 32768;

    k_transpose<<<dim3(256, 2), 256, 0, stream>>>(Wsf, Whp, Wts, Wth);
    k_pack_mask<<<2048, 256, 0, stream>>>(msk, pck);
    k_gemm_relu<<<dim3(64, 4, 2), 256, 0, stream>>>(pf, pm, nf, nm, Wts, Wth, bsf, bhp, hbuf);

    if (ws_size >= need) {
        k_transposeH<<<dim3(64, 4, 2), 256, 0, stream>>>(hbuf, hT);
        k_sort<<<dim3(256, 2), 256, 0, stream>>>(hT, srt, topkG, botkG);
        k_probe<<<dim3(256, 2), 256, 0, stream>>>(srt, topkG, botkG, pck, Wsc, bsc, out);
    } else {
        // small-ws fallback: round-13 brute-force pool (fits in 8.6 MB)
        k_pool9<<<dim3(1024, 2), 512, 0, stream>>>(hbuf, pck, Wsc, bsc, out);
    }
}

// Round 16
// 192.141 us; speedup vs baseline: 3.0459x; 1.1005x over previous
//
#include <hip/hip_runtime.h>
#include <hip/hip_bf16.h>
#include <hip/hip_fp16.h>

// N=4096 nodes, E=4096 hyperedges, F=256, H=256. All float tensors f32;
// batch_mask int32. out = 8192 f32: [pos_score | neg_score].

typedef short bf16x8 __attribute__((ext_vector_type(8)));
typedef float f32x4 __attribute__((ext_vector_type(4)));
typedef short s16x2 __attribute__((ext_vector_type(2)));
typedef unsigned short u16x2 __attribute__((ext_vector_type(2)));

static __device__ __forceinline__ unsigned short f2bf(float f) {
    __hip_bfloat16 b = __float2bfloat16(f);
    return __builtin_bit_cast(unsigned short, b);
}
static __device__ __forceinline__ float f16u_to_f(unsigned u) {
    __half h = __builtin_bit_cast(__half, (unsigned short)(u & 0xffffu));
    return __half2float(h);
}
static __device__ __forceinline__ unsigned pkmax_i16(unsigned a, unsigned b) {
    s16x2 r = __builtin_elementwise_max(__builtin_bit_cast(s16x2, a), __builtin_bit_cast(s16x2, b));
    return __builtin_bit_cast(unsigned, r);
}
static __device__ __forceinline__ unsigned pkmin_u16(unsigned a, unsigned b) {
    u16x2 r = __builtin_elementwise_min(__builtin_bit_cast(u16x2, a), __builtin_bit_cast(u16x2, b));
    return __builtin_bit_cast(unsigned, r);
}

// ---------------------------------------------------------------- prep: W transpose + mask pack (fused)
// bx < 2048: pack mask word bx*256+t (NON-inverted, MSB-first:
//   bit (31-j) of packed[e][w] = mask[e][w*32+j];
//   membership test for idx: (int)(word << (idx&31)) < 0).
// bx >= 2048: Wt[n][k] = bf16(W[k][n]).
__global__ void k_prep(const int* __restrict__ mask, unsigned* __restrict__ packed,
                       const float* __restrict__ Ws, const float* __restrict__ Wh,
                       unsigned short* __restrict__ Wts, unsigned short* __restrict__ Wth) {
    const int bx = blockIdx.x, t = threadIdx.x;
    if (bx < 2048) {
        int w = bx * 256 + t;
        const int* p = mask + (size_t)w * 32;
        unsigned word = 0;
#pragma unroll
        for (int j = 0; j < 32; j += 4) {
            int4 m = *(const int4*)(p + j);
            word |= (m.x != 0 ? (1u << (31 - j)) : 0u)
                  | (m.y != 0 ? (1u << (30 - j)) : 0u)
                  | (m.z != 0 ? (1u << (29 - j)) : 0u)
                  | (m.w != 0 ? (1u << (28 - j)) : 0u);
        }
        packed[w] = word;
    } else {
        int b2 = bx - 2048;            // 0..511
        int k = b2 & 255, brn = b2 >> 8;
        const float* W     = brn ? Wh : Ws;
        unsigned short* Wt = brn ? Wth : Wts;
        Wt[t * 256 + k] = f2bf(W[k * 256 + t]);
    }
}

// ---------------------------------------------------------------- GEMM + relu -> f16 h
__launch_bounds__(256)
__global__ void k_gemm_relu(const float* __restrict__ pXf, const float* __restrict__ pXm,
                            const float* __restrict__ nXf, const float* __restrict__ nXm,
                            const unsigned short* __restrict__ Wts, const unsigned short* __restrict__ Wth,
                            const float* __restrict__ bs,  const float* __restrict__ bh,
                            unsigned short* __restrict__ hAll /* f16 [2][4096][256] */) {
    const int t  = threadIdx.x;
    const int wv = t >> 6;
    const int l  = t & 63;
    const int lm = l & 15;
    const int q  = l >> 4;
    const int bz = blockIdx.z;
    const float* Xf = bz ? nXf : pXf;
    const float* Xm = bz ? nXm : pXm;
    unsigned short* hb = hAll + (size_t)bz * 4096 * 256;

    const int m0 = blockIdx.x * 64 + wv * 16;
    const int n0 = blockIdx.y * 64;

    f32x4 acc[4] = {};
#pragma unroll
    for (int ks = 0; ks < 512; ks += 32) {
        const float* X           = (ks < 256) ? Xf : Xm;
        const unsigned short* Wt = (ks < 256) ? Wts : Wth;
        const int kk = (ks & 255) + q * 8;
        float4 a0 = *(const float4*)(X + (m0 + lm) * 256 + kk);
        float4 a1 = *(const float4*)(X + (m0 + lm) * 256 + kk + 4);
        bf16x8 a;
        a[0] = (short)f2bf(a0.x); a[1] = (short)f2bf(a0.y);
        a[2] = (short)f2bf(a0.z); a[3] = (short)f2bf(a0.w);
        a[4] = (short)f2bf(a1.x); a[5] = (short)f2bf(a1.y);
        a[6] = (short)f2bf(a1.z); a[7] = (short)f2bf(a1.w);
#pragma unroll
        for (int nt = 0; nt < 4; nt++) {
            bf16x8 b = *(const bf16x8*)(Wt + (n0 + nt * 16 + lm) * 256 + kk);
            acc[nt] = __builtin_amdgcn_mfma_f32_16x16x32_bf16(a, b, acc[nt], 0, 0, 0);
        }
    }
#pragma unroll
    for (int nt = 0; nt < 4; nt++) {
        const int c = n0 + nt * 16 + lm;
        const float bsum = bs[c] + bh[c];
#pragma unroll
        for (int i = 0; i < 4; i++) {
            const int r = m0 + q * 4 + i;
            float v = acc[nt][i] + bsum;
            v = v > 0.f ? v : 0.f;   // relu => h >= +0.0 (u16-monotonic f16 bits)
            hb[r * 256 + c] = __builtin_bit_cast(unsigned short, __float2half(v));
        }
    }
}

// ---------------------------------------------------------------- h transpose -> hT [2][256][4096]
__global__ void k_transposeH(const unsigned short* __restrict__ h, unsigned short* __restrict__ hT) {
    __shared__ unsigned tile[64][65];
    const int r0 = blockIdx.x * 64, c0 = blockIdx.y * 64, br = blockIdx.z;
    const unsigned short* src = h + (size_t)br * 4096 * 256;
    unsigned short* dst = hT + (size_t)br * 256 * 4096;
    const int t = threadIdx.x;
#pragma unroll
    for (int m = 0; m < 16; m++) {
        int li = t + m * 256; int r = li >> 6, c = li & 63;
        tile[r][c] = src[(size_t)(r0 + r) * 256 + c0 + c];
    }
    __syncthreads();
#pragma unroll
    for (int m = 0; m < 16; m++) {
        int li = t + m * 256; int c = li >> 6, r = li & 63;
        dst[(size_t)(c0 + c) * 4096 + r0 + r] = (unsigned short)tile[r][c];
    }
}

// ---------------------------------------------------------------- per-column LSD radix sort
// One block per (col, branch). keys = (f16bits << 16) | idx; 4 passes x
// 4-bit digits over the value field. Per-thread histograms + flattened
// exclusive scan -> stable deterministic ranks, no atomics. Wave sums are
// parked in the scatter-destination buffer (free until 2 barriers later),
// keeping LDS at exactly 40 KB -> 4 blocks/CU. grid (256, 2), block 256.
__launch_bounds__(256)
__global__ void k_sort(const unsigned short* __restrict__ hT,
                       unsigned* __restrict__ sortedAsc,
                       unsigned* __restrict__ topkG, unsigned* __restrict__ botkG) {
    __shared__ unsigned arrA[4096];              // 16 KB
    __shared__ unsigned arrB[4096];              // 16 KB
    __shared__ unsigned short hist[16 * 256];    // 8 KB, flattened [bin*256 + thread]

    const int c = blockIdx.x, br = blockIdx.y, t = threadIdx.x;
    const int wv = t >> 6, l = t & 63;
    const unsigned short* src = hT + (size_t)(br * 256 + c) * 4096;

    {   // load 16 consecutive u16 per thread, build keys
        uint4 a = ((const uint4*)src)[t * 2];
        uint4 b = ((const uint4*)src)[t * 2 + 1];
        unsigned base = t * 16;
        unsigned w[8] = {a.x, a.y, a.z, a.w, b.x, b.y, b.z, b.w};
#pragma unroll
        for (int m = 0; m < 8; m++) {
            arrA[base + 2 * m]     = ((w[m] & 0xFFFFu) << 16) | (base + 2 * m);
            arrA[base + 2 * m + 1] = (w[m] & 0xFFFF0000u)     | (base + 2 * m + 1);
        }
    }
    __syncthreads();

    unsigned* A = arrA;
    unsigned* B = arrB;
#pragma unroll
    for (int pass = 0; pass < 4; pass++) {
        const int sh = 16 + pass * 4;
        unsigned keys[16];
        unsigned short cnt[16];
#pragma unroll
        for (int b = 0; b < 16; b++) cnt[b] = 0;
#pragma unroll
        for (int m = 0; m < 16; m++) {
            keys[m] = A[t * 16 + m];
            cnt[(keys[m] >> sh) & 15u]++;
        }
#pragma unroll
        for (int b = 0; b < 16; b++) hist[b * 256 + t] = cnt[b];
        __syncthreads();

        // exclusive scan of the flattened 4096-entry histogram
        unsigned loc[16];
        unsigned sum = 0;
#pragma unroll
        for (int m = 0; m < 16; m++) { loc[m] = sum; sum += hist[t * 16 + m]; }
        unsigned ws = sum;
#pragma unroll
        for (int off = 1; off < 64; off <<= 1) {
            unsigned n = __shfl_up(ws, off);
            if (l >= off) ws += n;
        }
        if (l == 63) B[wv] = ws;     // park wave sum in scatter dest (free here)
        __syncthreads();
        unsigned wbase = 0;
#pragma unroll
        for (int w2 = 0; w2 < 4; w2++) if (w2 < wv) wbase += B[w2];
        const unsigned ex = wbase + ws - sum;
#pragma unroll
        for (int m = 0; m < 16; m++) hist[t * 16 + m] = (unsigned short)(ex + loc[m]);
        __syncthreads();

        // deterministic scatter via register offsets
        unsigned offs[16];
#pragma unroll
        for (int b = 0; b < 16; b++) offs[b] = hist[b * 256 + t];
#pragma unroll
        for (int m = 0; m < 16; m++) {
            unsigned b = (keys[m] >> sh) & 15u;
            B[offs[b]++] = keys[m];
        }
        __syncthreads();
        unsigned* tmp = A; A = B; B = tmp;
    }
    // 4 passes (even) -> result back in arrA, ascending by value

    unsigned* outp = sortedAsc + (size_t)(br * 256 + c) * 4096;
#pragma unroll
    for (int m = 0; m < 16; m++) { int i = t + m * 256; outp[i] = arrA[i]; }
    if (t < 16) {
        topkG[(br * 16 + t) * 256 + c] = arrA[4095 - t];   // descending from max
        botkG[(br * 16 + t) * 256 + c] = arrA[t];          // ascending from min
    }
}

// ---------------------------------------------------------------- probe + score
// Block: 16 edges x one branch; 4 waves x 4 edges. Lane l covers cols
// c = l + 64*sl. Probes batched 8-WIDE: 8 independent key loads then 8
// independent mask tests then priority select -- cuts the dependent-LDS
// chain ~8x vs scalar probing (wave advances only when all 64 lanes hit;
// P(lane needs >8 probes) = 2^-8 -> typically one group). Global sortedAsc
// fallback (p>=16) is exact. LDS 40 KB. grid (256, 2), block 256.
__launch_bounds__(256)
__global__ void k_probe(const unsigned* __restrict__ sortedAsc,
                        const unsigned* __restrict__ topkG,
                        const unsigned* __restrict__ botkG,
                        const unsigned* __restrict__ packed,
                        const float* __restrict__ Wscore,
                        const float* __restrict__ bscore,
                        float* __restrict__ out) {
    __shared__ __align__(16) unsigned topkL[16 * 256];   // [p][c] 16 KB
    __shared__ __align__(16) unsigned botkL[16 * 256];   // [p][c] 16 KB
    __shared__ __align__(16) unsigned bitsL[16 * 128];   // 8 KB

    const int t  = threadIdx.x;
    const int wv = t >> 6;
    const int l  = t & 63;
    const int e0 = blockIdx.x * 16;
    const int br = blockIdx.y;

    {
        const uint4* ts  = (const uint4*)(topkG + br * 4096);
        const uint4* bs2 = (const uint4*)(botkG + br * 4096);
#pragma unroll
        for (int m = 0; m < 4; m++) {
            ((uint4*)topkL)[t + m * 256] = ts[t + m * 256];
            ((uint4*)botkL)[t + m * 256] = bs2[t + m * 256];
        }
        ((uint4*)bitsL)[t]       = ((const uint4*)(packed + e0 * 128))[t];
        ((uint4*)bitsL)[t + 256] = ((const uint4*)(packed + e0 * 128))[t + 256];
    }
    __syncthreads();

    const float bsc = *bscore;
    float wsv[4];
#pragma unroll
    for (int sl = 0; sl < 4; sl++) wsv[sl] = Wscore[l + 64 * sl];

#pragma unroll 1
    for (int k = 0; k < 4; k++) {
        const int e = wv * 4 + k;
        const unsigned* mk = &bitsL[e * 128];
        float s = 0.f;
#pragma unroll
        for (int sl = 0; sl < 4; sl++) {
            const int c = l + 64 * sl;
            const unsigned* gs = sortedAsc + (size_t)(br * 256 + c) * 4096;

            // ---- MAX: first member in descending order
            unsigned sel = 0xFFFFFFFFu;   // > any real key (value<=0x7C00)
#pragma unroll 1
            for (int g = 0; g < 2; g++) {
                unsigned kk[8]; int ss[8];
#pragma unroll
                for (int j = 0; j < 8; j++) kk[j] = topkL[(g * 8 + j) * 256 + c];
#pragma unroll
                for (int j = 0; j < 8; j++)
                    ss[j] = (int)(mk[(kk[j] & 4095u) >> 5] << (kk[j] & 31u));
                unsigned fnd = 0xFFFFFFFFu;
#pragma unroll
                for (int j = 7; j >= 0; j--) if (ss[j] < 0) fnd = kk[j];
                if (fnd != 0xFFFFFFFFu) { sel = fnd; break; }
            }
            if (sel == 0xFFFFFFFFu) {
#pragma unroll 1
                for (int p = 16; p < 4096; p++) {
                    unsigned key = gs[4095 - p];
                    if ((int)(mk[(key & 4095u) >> 5] << (key & 31u)) < 0) { sel = key; break; }
                }
            }
            const float vmax = f16u_to_f(sel >> 16);

            // ---- MIN: first member in ascending order
            sel = 0xFFFFFFFFu;
#pragma unroll 1
            for (int g = 0; g < 2; g++) {
                unsigned kk[8]; int ss[8];
#pragma unroll
                for (int j = 0; j < 8; j++) kk[j] = botkL[(g * 8 + j) * 256 + c];
#pragma unroll
                for (int j = 0; j < 8; j++)
                    ss[j] = (int)(mk[(kk[j] & 4095u) >> 5] << (kk[j] & 31u));
                unsigned fnd = 0xFFFFFFFFu;
#pragma unroll
                for (int j = 7; j >= 0; j--) if (ss[j] < 0) fnd = kk[j];
                if (fnd != 0xFFFFFFFFu) { sel = fnd; break; }
            }
            if (sel == 0xFFFFFFFFu) {
#pragma unroll 1
                for (int p = 16; p < 4096; p++) {
                    unsigned key = gs[p];
                    if ((int)(mk[(key & 4095u) >> 5] << (key & 31u)) < 0) { sel = key; break; }
                }
            }
            const float vmin = f16u_to_f(sel >> 16);

            s += (vmax - vmin) * wsv[sl];
        }
#pragma unroll
        for (int off = 32; off; off >>= 1) s += __shfl_xor(s, off);
        if (l == 0)
            out[br * 4096 + e0 + e] = 1.f / (1.f + __expf(-(s + bsc)));
    }
}

// ================================================================ fallback
// Round-13 proven pool (brute-force member-skip scan) for small-ws safety.
#define POOL_STEP(WE, MX0, MX1, MN0, MN1, VX, VY)                          \
    {                                                                      \
        asm("s_add_u32 %[we], %[we], %[we]\n\t"                            \
            "s_cbranch_scc0 Lskip%=\n\t"                                   \
            "v_pk_max_i16 %[mx0], %[mx0], %[vx]\n\t"                       \
            "v_pk_max_i16 %[mx1], %[mx1], %[vy]\n\t"                       \
            "v_pk_min_u16 %[mn0], %[mn0], %[vx]\n\t"                       \
            "v_pk_min_u16 %[mn1], %[mn1], %[vy]\n"                         \
            "Lskip%=:"                                                     \
            : [we] "+s"(WE),                                               \
              [mx0] "+v"(MX0), [mx1] "+v"(MX1),                            \
              [mn0] "+v"(MN0), [mn1] "+v"(MN1)                             \
            : [vx] "v"(VX), [vy] "v"(VY)                                   \
            : "scc");                                                      \
    }

__launch_bounds__(512, 8)
__global__ void k_pool9(const unsigned short* __restrict__ hAll,
                        const unsigned* __restrict__ packed,
                        const float* __restrict__ Wscore,
                        const float* __restrict__ bscore,
                        float* __restrict__ out) {
    __shared__ __align__(16) unsigned bits[4 * 128];
    __shared__ __align__(16) unsigned part[8][4][64][4];

    const int t  = threadIdx.x;
    const int wv = t >> 6;
    const int l  = t & 63;
    const int e0 = blockIdx.x * 4;
    const int br = blockIdx.y;
    const unsigned short* h = hAll + (size_t)br * 4096 * 256;

    if (t < 128) ((uint4*)bits)[t] = ((const uint4*)(packed + e0 * 128))[t];
    __syncthreads();

    unsigned mx0[4], mx1[4], mn0[4], mn1[4];
#pragma unroll
    for (int e = 0; e < 4; e++) {
        mx0[e] = 0x80008000u; mx1[e] = 0x80008000u;
        mn0[e] = 0xFFFFFFFFu; mn1[e] = 0xFFFFFFFFu;
    }

#pragma unroll 1
    for (int ch = 0; ch < 16; ch++) {
        const int w0 = wv * 16 + ch;
        unsigned we0 = (unsigned)__builtin_amdgcn_readfirstlane((int)bits[0 * 128 + w0]);
        unsigned we1 = (unsigned)__builtin_amdgcn_readfirstlane((int)bits[1 * 128 + w0]);
        unsigned we2 = (unsigned)__builtin_amdgcn_readfirstlane((int)bits[2 * 128 + w0]);
        unsigned we3 = (unsigned)__builtin_amdgcn_readfirstlane((int)bits[3 * 128 + w0]);

        const unsigned short* hp = h + (size_t)(wv * 512 + ch * 32) * 256 + 4 * l;
#pragma unroll
        for (int jj = 0; jj < 8; jj++) {
            uint2 v0 = *(const uint2*)(hp + (jj * 4 + 0) * 256);
            uint2 v1 = *(const uint2*)(hp + (jj * 4 + 1) * 256);
            uint2 v2 = *(const uint2*)(hp + (jj * 4 + 2) * 256);
            uint2 v3 = *(const uint2*)(hp + (jj * 4 + 3) * 256);

            POOL_STEP(we0, mx0[0], mx1[0], mn0[0], mn1[0], v0.x, v0.y);
            POOL_STEP(we1, mx0[1], mx1[1], mn0[1], mn1[1], v0.x, v0.y);
            POOL_STEP(we2, mx0[2], mx1[2], mn0[2], mn1[2], v0.x, v0.y);
            POOL_STEP(we3, mx0[3], mx1[3], mn0[3], mn1[3], v0.x, v0.y);
            POOL_STEP(we0, mx0[0], mx1[0], mn0[0], mn1[0], v1.x, v1.y);
            POOL_STEP(we1, mx0[1], mx1[1], mn0[1], mn1[1], v1.x, v1.y);
            POOL_STEP(we2, mx0[2], mx1[2], mn0[2], mn1[2], v1.x, v1.y);
            POOL_STEP(we3, mx0[3], mx1[3], mn0[3], mn1[3], v1.x, v1.y);
            POOL_STEP(we0, mx0[0], mx1[0], mn0[0], mn1[0], v2.x, v2.y);
            POOL_STEP(we1, mx0[1], mx1[1], mn0[1], mn1[1], v2.x, v2.y);
            POOL_STEP(we2, mx0[2], mx1[2], mn0[2], mn1[2], v2.x, v2.y);
            POOL_STEP(we3, mx0[3], mx1[3], mn0[3], mn1[3], v2.x, v2.y);
            POOL_STEP(we0, mx0[0], mx1[0], mn0[0], mn1[0], v3.x, v3.y);
            POOL_STEP(we1, mx0[1], mx1[1], mn0[1], mn1[1], v3.x, v3.y);
            POOL_STEP(we2, mx0[2], mx1[2], mn0[2], mn1[2], v3.x, v3.y);
            POOL_STEP(we3, mx0[3], mx1[3], mn0[3], mn1[3], v3.x, v3.y);
        }
    }

#pragma unroll
    for (int e = 0; e < 4; e++) {
        uint4 p; p.x = mx0[e]; p.y = mx1[e]; p.z = mn0[e]; p.w = mn1[e];
        *(uint4*)&part[wv][e][l][0] = p;
    }
    __syncthreads();

    if (wv < 4) {
        unsigned rmx0 = 0x80008000u, rmx1 = 0x80008000u;
        unsigned rmn0 = 0xFFFFFFFFu, rmn1 = 0xFFFFFFFFu;
#pragma unroll
        for (int w2 = 0; w2 < 8; w2++) {
            uint4 p = *(const uint4*)&part[w2][wv][l][0];
            rmx0 = pkmax_i16(rmx0, p.x);  rmx1 = pkmax_i16(rmx1, p.y);
            rmn0 = pkmin_u16(rmn0, p.z);  rmn1 = pkmin_u16(rmn1, p.w);
        }
        float4 wsv = *(const float4*)(Wscore + 4 * l);
        const float bsc = *bscore;
        float s = (f16u_to_f(rmx0)       - f16u_to_f(rmn0))       * wsv.x
                + (f16u_to_f(rmx0 >> 16) - f16u_to_f(rmn0 >> 16)) * wsv.y
                + (f16u_to_f(rmx1)       - f16u_to_f(rmn1))       * wsv.z
                + (f16u_to_f(rmx1 >> 16) - f16u_to_f(rmn1 >> 16)) * wsv.w;
#pragma unroll
        for (int off = 32; off; off >>= 1) s += __shfl_xor(s, off);
        if (l == 0)
            out[br * 4096 + e0 + wv] = 1.f / (1.f + __expf(-(s + bsc)));
    }
}

// ---------------------------------------------------------------- launch
extern "C" void kernel_launch(void* const* d_in, const int* in_sizes, int n_in,
                              void* d_out, int out_size, void* d_ws, size_t ws_size,
                              hipStream_t stream) {
    const float* pf  = (const float*)d_in[0];
    const float* pm  = (const float*)d_in[1];
    const float* nf  = (const float*)d_in[2];
    const float* nm  = (const float*)d_in[3];
    const int*   msk = (const int*)d_in[4];
    const float* Wsf = (const float*)d_in[5];
    const float* bsf = (const float*)d_in[6];
    const float* Whp = (const float*)d_in[7];
    const float* bhp = (const float*)d_in[8];
    const float* Wsc = (const float*)d_in[9];
    const float* bsc = (const float*)d_in[10];
    float* out = (float*)d_out;

    char* ws = (char*)d_ws;
    const size_t MB = 1024u * 1024u;
    unsigned short* hbuf  = (unsigned short*)(ws);                 // 4 MB  [2][4096][256]
    unsigned short* hT    = (unsigned short*)(ws + 4 * MB);        // 4 MB  [2][256][4096]
    unsigned*       srt   = (unsigned*)(ws + 8 * MB);              // 8 MB  [2][256][4096]
    unsigned*       pck   = (unsigned*)(ws + 16 * MB);             // 2 MB  [4096][128]
    unsigned short* Wts   = (unsigned short*)(ws + 18 * MB);       // 128 KB
    unsigned short* Wth   = Wts + 256 * 256;                       // 128 KB
    unsigned*       topkG = (unsigned*)(ws + 18 * MB + 256 * 1024);          // 32 KB
    unsigned*       botkG = (unsigned*)(ws + 18 * MB + 256 * 1024 + 32768);  // 32 KB
    const size_t need = 18 * MB + 256 * 1024 + 2 * 32768;

    k_prep<<<2560, 256, 0, stream>>>(msk, pck, Wsf, Whp, Wts, Wth);
    k_gemm_relu<<<dim3(64, 4, 2), 256, 0, stream>>>(pf, pm, nf, nm, Wts, Wth, bsf, bhp, hbuf);

    if (ws_size >= need) {
        k_transposeH<<<dim3(64, 4, 2), 256, 0, stream>>>(hbuf, hT);
        k_sort<<<dim3(256, 2), 256, 0, stream>>>(hT, srt, topkG, botkG);
        k_probe<<<dim3(256, 2), 256, 0, stream>>>(srt, topkG, botkG, pck, Wsc, bsc, out);
    } else {
        // small-ws fallback: round-13 brute-force pool (fits in 8.6 MB)
        k_pool9<<<dim3(1024, 2), 512, 0, stream>>>(hbuf, pck, Wsc, bsc, out);
    }
}